// Round 2
// baseline (691.058 us; speedup 1.0000x reference)
//
#include <hip/hip_runtime.h>
#include <stdint.h>

typedef unsigned short u16;
typedef float f32x4 __attribute__((ext_vector_type(4)));
typedef __bf16 bf16x8 __attribute__((ext_vector_type(8)));
typedef u16 u16x8 __attribute__((ext_vector_type(8)));

#define NHEADS 16
#define NKV 4
#define HD 64
#define HDIM 1024
#define FDIM 2048
#define SLEN 1024
#define BATCH 4
#define TTOK 4096
#define NEXP 8
#define QKVO 1536

__device__ __forceinline__ u16 f2bf(float f) {
  union { float f; uint32_t u; } c; c.f = f;
  uint32_t u = c.u;
  return (u16)((u + 0x7FFFu + ((u >> 16) & 1u)) >> 16);
}
__device__ __forceinline__ float bf2f(u16 h) {
  union { uint32_t u; float f; } c; c.u = ((uint32_t)h) << 16; return c.f;
}
__device__ __forceinline__ void split2(float v, u16& h, u16& l) {
  h = f2bf(v);
  l = f2bf(v - bf2f(h));
}

__device__ __forceinline__ f32x4 mfma16(bf16x8 a, bf16x8 b, f32x4 c) {
  return __builtin_amdgcn_mfma_f32_16x16x32_bf16(a, b, c, 0, 0, 0);
}

__device__ __forceinline__ bf16x8 lds_frag(const u16* base) {
  u16x8 v = *(const u16x8*)base;
  return __builtin_bit_cast(bf16x8, v);
}

__device__ __forceinline__ void gload_lds16(const void* g, void* l) {
  __builtin_amdgcn_global_load_lds((const __attribute__((address_space(1))) void*)g,
                                   (__attribute__((address_space(3))) void*)l, 16, 0, 0);
}

// ---------------- fp32 -> split bf16 (hi/lo) convert ----------------
__global__ __launch_bounds__(256)
void cvt_split_kernel(const float* __restrict__ in, u16* __restrict__ oh,
                      u16* __restrict__ ol, int n4) {
  int i = blockIdx.x * blockDim.x + threadIdx.x;
  if (i < n4) {
    float4 v = ((const float4*)in)[i];
    ushort4 h, l;
    split2(v.x, h.x, l.x); split2(v.y, h.y, l.y);
    split2(v.z, h.z, l.z); split2(v.w, h.w, l.w);
    ((ushort4*)oh)[i] = h;
    ((ushort4*)ol)[i] = l;
  }
}

// ---------------- tiled transpose + convert: in [R][C] f32 -> out [C][R] bf16, z = expert ----------------
__global__ __launch_bounds__(256)
void transpose_cvt_kernel(const float* __restrict__ in, u16* __restrict__ out, int R, int C) {
  __shared__ float tile[32][33];
  size_t eoff = (size_t)blockIdx.z * (size_t)R * (size_t)C;
  in += eoff; out += eoff;
  int c0 = blockIdx.x * 32, r0 = blockIdx.y * 32;
  int tx = threadIdx.x, ty = threadIdx.y;
#pragma unroll
  for (int i = 0; i < 4; i++)
    tile[ty + i * 8][tx] = in[(size_t)(r0 + ty + i * 8) * C + c0 + tx];
  __syncthreads();
#pragma unroll
  for (int i = 0; i < 4; i++)
    out[(size_t)(c0 + ty + i * 8) * R + r0 + tx] = f2bf(tile[tx][ty + i * 8]);
}

// ---------------- LayerNorm: fp32 row -> split bf16 (+ optional fp32) ----------------
__global__ __launch_bounds__(256)
void ln_kernel(const float* __restrict__ x, const float* __restrict__ w,
               const float* __restrict__ bias, u16* __restrict__ oh,
               u16* __restrict__ ol, float* __restrict__ of32) {
  int t = blockIdx.x, tid = threadIdx.x;
  int wid = tid >> 6, lane = tid & 63;
  float4 v = ((const float4*)(x + (size_t)t * HDIM))[tid];
  float s = v.x + v.y + v.z + v.w;
  float q = v.x * v.x + v.y * v.y + v.z * v.z + v.w * v.w;
#pragma unroll
  for (int mm = 32; mm >= 1; mm >>= 1) {
    s += __shfl_xor(s, mm);
    q += __shfl_xor(q, mm);
  }
  __shared__ float ss[4], qq[4];
  if (lane == 0) { ss[wid] = s; qq[wid] = q; }
  __syncthreads();
  s = ss[0] + ss[1] + ss[2] + ss[3];
  q = qq[0] + qq[1] + qq[2] + qq[3];
  float mu = s * (1.0f / HDIM);
  float var = q * (1.0f / HDIM) - mu * mu;
  float inv = rsqrtf(var + 1e-5f);
  float4 wv = ((const float4*)w)[tid];
  float4 bv = ((const float4*)bias)[tid];
  float y0 = (v.x - mu) * inv * wv.x + bv.x;
  float y1 = (v.y - mu) * inv * wv.y + bv.y;
  float y2 = (v.z - mu) * inv * wv.z + bv.z;
  float y3 = (v.w - mu) * inv * wv.w + bv.w;
  ushort4 h, l;
  split2(y0, h.x, l.x); split2(y1, h.y, l.y);
  split2(y2, h.z, l.z); split2(y3, h.w, l.w);
  ((ushort4*)(oh + (size_t)t * HDIM))[tid] = h;
  if (ol) ((ushort4*)(ol + (size_t)t * HDIM))[tid] = l;
  if (of32) {
    float4 yo; yo.x = y0; yo.y = y1; yo.z = y2; yo.w = y3;
    ((float4*)(of32 + (size_t)t * HDIM))[tid] = yo;
  }
}

// ---------------- precision GEMM: C = (Ah+Al)(Bh+Bl)^T, 3-term compensated ----------------
// MODE 0: outf = C ; MODE 1: outf = C + resid
template<int MODE>
__global__ __launch_bounds__(256)
void gemm_split(const u16* __restrict__ Ah, const u16* __restrict__ Al,
                const u16* __restrict__ Bh, const u16* __restrict__ Bl,
                int M, int N, int K,
                const float* __restrict__ resid, float* __restrict__ outf) {
  int tid = threadIdx.x;
  int wid = tid >> 6, lane = tid & 63;
  int l15 = lane & 15, l4 = lane >> 4;
  int bn = blockIdx.x, bm = blockIdx.y;

  __shared__ u16 sAh[128 * 64], sAl[128 * 64], sBh[128 * 64], sBl[128 * 64];

  int slot = tid & 7;
  size_t aG[4], bG[4];
#pragma unroll
  for (int i = 0; i < 4; i++) {
    int r = i * 32 + (tid >> 3);
    int sl = slot ^ (r & 7);
    aG[i] = (size_t)(bm * 128 + r) * K + sl * 8;
    bG[i] = (size_t)(bn * 128 + r) * K + sl * 8;
  }

  int wm = (wid >> 1) * 64, wn = (wid & 1) * 64;
  f32x4 zero4 = {0.f, 0.f, 0.f, 0.f};
  f32x4 acc[4][4];
#pragma unroll
  for (int mi = 0; mi < 4; mi++)
#pragma unroll
    for (int ni = 0; ni < 4; ni++) acc[mi][ni] = zero4;

  int aoff[4][2], boff[4][2];
#pragma unroll
  for (int mi = 0; mi < 4; mi++) {
    int row = wm + mi * 16 + l15;
#pragma unroll
    for (int kk = 0; kk < 2; kk++) {
      int cs = kk * 4 + l4;
      aoff[mi][kk] = row * 64 + ((cs ^ (row & 7)) << 3);
    }
  }
#pragma unroll
  for (int ni = 0; ni < 4; ni++) {
    int row = wn + ni * 16 + l15;
#pragma unroll
    for (int kk = 0; kk < 2; kk++) {
      int cs = kk * 4 + l4;
      boff[ni][kk] = row * 64 + ((cs ^ (row & 7)) << 3);
    }
  }

  int nk = K >> 6;
  for (int kt = 0; kt < nk; ++kt) {
    int k0 = kt << 6;
    __syncthreads();
#pragma unroll
    for (int i = 0; i < 4; i++) {
      int d = (i * 256 + wid * 64) * 8;
      gload_lds16(Ah + aG[i] + k0, &sAh[d]);
      gload_lds16(Al + aG[i] + k0, &sAl[d]);
      gload_lds16(Bh + bG[i] + k0, &sBh[d]);
      gload_lds16(Bl + bG[i] + k0, &sBl[d]);
    }
    __syncthreads();
#pragma unroll
    for (int kk = 0; kk < 2; kk++) {
      bf16x8 ah[4], al[4], bh[4], bl[4];
#pragma unroll
      for (int mi = 0; mi < 4; mi++) {
        ah[mi] = lds_frag(&sAh[aoff[mi][kk]]);
        al[mi] = lds_frag(&sAl[aoff[mi][kk]]);
      }
#pragma unroll
      for (int ni = 0; ni < 4; ni++) {
        bh[ni] = lds_frag(&sBh[boff[ni][kk]]);
        bl[ni] = lds_frag(&sBl[boff[ni][kk]]);
      }
#pragma unroll
      for (int mi = 0; mi < 4; mi++)
#pragma unroll
        for (int ni = 0; ni < 4; ni++) {
          acc[mi][ni] = mfma16(ah[mi], bh[ni], acc[mi][ni]);
          acc[mi][ni] = mfma16(ah[mi], bl[ni], acc[mi][ni]);
          acc[mi][ni] = mfma16(al[mi], bh[ni], acc[mi][ni]);
        }
    }
  }

#pragma unroll
  for (int mi = 0; mi < 4; mi++) {
#pragma unroll
    for (int r = 0; r < 4; r++) {
      int m = bm * 128 + wm + mi * 16 + l4 * 4 + r;
#pragma unroll
      for (int ni = 0; ni < 4; ni++) {
        int n = bn * 128 + wn + ni * 16 + l15;
        float v = acc[mi][ni][r];
        size_t idx = (size_t)m * N + n;
        if constexpr (MODE == 0) {
          outf[idx] = v;
        } else {
          outf[idx] = v + resid[idx];
        }
      }
    }
  }
}

// ---------------- scatter QKV fp32 -> split bf16 per-head layout ----------------
__global__ __launch_bounds__(256)
void qkv_scatter(const float* __restrict__ C,
                 u16* __restrict__ Qh, u16* __restrict__ Ql,
                 u16* __restrict__ Kh, u16* __restrict__ Kl,
                 u16* __restrict__ Vh, u16* __restrict__ Vl) {
  int n = blockIdx.x * 256 + threadIdx.x;
  int m = blockIdx.y;
  float v = C[(size_t)m * QKVO + n];
  u16 h, l; split2(v, h, l);
  int sq = m >> 2, bb = m & 3;
  int d = n & 63;
  if (n < 1024) {
    int hh = n >> 6;
    size_t o = ((size_t)(bb * NHEADS + hh) * SLEN + sq) * HD + d;
    Qh[o] = h; Ql[o] = l;
  } else if (n < 1280) {
    int hh = (n - 1024) >> 6;
    size_t o = ((size_t)(bb * NKV + hh) * SLEN + sq) * HD + d;
    Kh[o] = h; Kl[o] = l;
  } else {
    int hh = (n - 1280) >> 6;
    size_t o = ((size_t)(bb * NKV + hh) * SLEN + sq) * HD + d;
    Vh[o] = h; Vl[o] = l;
  }
}

// ---------------- grouped MoE GEMM (single bf16): C[M,N] = A[M,K] * B[N,K]^T ----------------
// MODE 2: w1 (gathered A rows) -> gelu -> o0 bf16
// MODE 3: w2 (contiguous A)    -> outf fp32 scaled by wts
template<int MODE>
__global__ __launch_bounds__(256)
void gemm_moe(const u16* __restrict__ A0, const u16* __restrict__ B0,
              int N, int K, float* __restrict__ outf, u16* __restrict__ o0,
              const int* __restrict__ offs, const int* __restrict__ rowsIdx,
              const float* __restrict__ wts) {
  int tid = threadIdx.x;
  int wid = tid >> 6, lane = tid & 63;
  int l15 = lane & 15, l4 = lane >> 4;
  int bn = blockIdx.x, bm = blockIdx.y, e = blockIdx.z;

  int oa = offs[e], ob = offs[e + 1];
  int Me = ob - oa, rowBase = oa;
  const u16* A = A0;
  const u16* B = B0 + (size_t)e * (size_t)N * (size_t)K;
  if constexpr (MODE == 3) A = A0 + (size_t)oa * (size_t)K;
  if (bm * 128 >= Me) return;

  __shared__ u16 lsA[2][128 * 64];
  __shared__ u16 lsB[2][128 * 64];

  int slot = tid & 7;
  const u16* aPtr[4];
  const u16* bPtr[4];
#pragma unroll
  for (int i = 0; i < 4; i++) {
    int r = i * 32 + (tid >> 3);
    int sl = slot ^ (r & 7);
    int rg = bm * 128 + r;
    if constexpr (MODE == 2) {
      int rc = rg < Me ? rg : (Me - 1);
      rg = rowsIdx[rowBase + rc];
    } else {
      rg = rg < Me ? rg : (Me - 1);
    }
    aPtr[i] = A + (size_t)rg * K + sl * 8;
    int ng = bn * 128 + r;
    bPtr[i] = B + (size_t)ng * K + sl * 8;
  }

  int wm = (wid >> 1) * 64, wn = (wid & 1) * 64;
  f32x4 zero4 = {0.f, 0.f, 0.f, 0.f};
  f32x4 acc[4][4];
#pragma unroll
  for (int mi = 0; mi < 4; mi++)
#pragma unroll
    for (int ni = 0; ni < 4; ni++) acc[mi][ni] = zero4;

  int aoff[4][2], boff[4][2];
#pragma unroll
  for (int mi = 0; mi < 4; mi++) {
    int row = wm + mi * 16 + l15;
#pragma unroll
    for (int kk = 0; kk < 2; kk++) {
      int cs = kk * 4 + l4;
      aoff[mi][kk] = row * 64 + ((cs ^ (row & 7)) << 3);
    }
  }
#pragma unroll
  for (int ni = 0; ni < 4; ni++) {
    int row = wn + ni * 16 + l15;
#pragma unroll
    for (int kk = 0; kk < 2; kk++) {
      int cs = kk * 4 + l4;
      boff[ni][kk] = row * 64 + ((cs ^ (row & 7)) << 3);
    }
  }

  int nk = K >> 6;
#pragma unroll
  for (int i = 0; i < 4; i++) {
    gload_lds16(aPtr[i], &lsA[0][(i * 256 + wid * 64) * 8]);
    gload_lds16(bPtr[i], &lsB[0][(i * 256 + wid * 64) * 8]);
  }
  __syncthreads();

  int buf = 0;
  for (int kt = 0; kt < nk; ++kt) {
    if (kt + 1 < nk) {
      int k0 = (kt + 1) << 6;
#pragma unroll
      for (int i = 0; i < 4; i++) {
        gload_lds16(aPtr[i] + k0, &lsA[buf ^ 1][(i * 256 + wid * 64) * 8]);
        gload_lds16(bPtr[i] + k0, &lsB[buf ^ 1][(i * 256 + wid * 64) * 8]);
      }
    }
#pragma unroll
    for (int kk = 0; kk < 2; kk++) {
      bf16x8 af[4], bfr[4];
#pragma unroll
      for (int mi = 0; mi < 4; mi++) af[mi] = lds_frag(&lsA[buf][aoff[mi][kk]]);
#pragma unroll
      for (int ni = 0; ni < 4; ni++) bfr[ni] = lds_frag(&lsB[buf][boff[ni][kk]]);
#pragma unroll
      for (int mi = 0; mi < 4; mi++)
#pragma unroll
        for (int ni = 0; ni < 4; ni++)
          acc[mi][ni] = mfma16(af[mi], bfr[ni], acc[mi][ni]);
    }
    __syncthreads();
    buf ^= 1;
  }

#pragma unroll
  for (int mi = 0; mi < 4; mi++) {
#pragma unroll
    for (int r = 0; r < 4; r++) {
      int m = bm * 128 + wm + mi * 16 + l4 * 4 + r;
      if (m >= Me) continue;
#pragma unroll
      for (int ni = 0; ni < 4; ni++) {
        int n = bn * 128 + wn + ni * 16 + l15;
        float v = acc[mi][ni][r];
        if constexpr (MODE == 2) {
          float g = 0.5f * v * (1.0f + tanhf(0.7978845608f * (v + 0.044715f * v * v * v)));
          o0[(size_t)(rowBase + m) * FDIM + n] = f2bf(g);
        } else {
          outf[(size_t)(rowBase + m) * HDIM + n] = v * wts[rowBase + m];
        }
      }
    }
  }
}

// ---------------- flash attention, causal, GQA, split precision ----------------
__global__ __launch_bounds__(256)
void attn_kernel(const u16* __restrict__ Qh_, const u16* __restrict__ Ql_,
                 const u16* __restrict__ Kh_, const u16* __restrict__ Kl_,
                 const u16* __restrict__ Vh_, const u16* __restrict__ Vl_,
                 u16* __restrict__ Oh_, u16* __restrict__ Ol_) {
  int qt = blockIdx.x;
  int bh = blockIdx.y;
  int b = bh >> 4, h = bh & 15, kh = h >> 2;
  int tid = threadIdx.x, wid = tid >> 6, lane = tid & 63;
  int l15 = lane & 15, l4 = lane >> 4;
  int slot = tid & 7;

  size_t qoff = ((size_t)(b * NHEADS + h) * SLEN) * HD;
  size_t koff = ((size_t)(b * NKV + kh) * SLEN) * HD;
  const u16* Qh = Qh_ + qoff;
  const u16* Ql = Ql_ + qoff;
  const u16* Kh = Kh_ + koff;
  const u16* Kl = Kl_ + koff;
  const u16* Vh = Vh_ + koff;
  const u16* Vl = Vl_ + koff;

  __shared__ u16 KtH[64 * 64], KtL[64 * 64];
  __shared__ u16 VtH[64 * 64], VtL[64 * 64];
  __shared__ u16 PtH[4][16 * 64], PtL[4][16 * 64];

  int qrow = qt * 64 + wid * 16 + l15;
  bf16x8 qfh[2], qfl[2];
#pragma unroll
  for (int kk = 0; kk < 2; kk++) {
    u16x8 vh = *(const u16x8*)(Qh + (size_t)qrow * HD + kk * 32 + l4 * 8);
    u16x8 vl = *(const u16x8*)(Ql + (size_t)qrow * HD + kk * 32 + l4 * 8);
    qfh[kk] = __builtin_bit_cast(bf16x8, vh);
    qfl[kk] = __builtin_bit_cast(bf16x8, vl);
  }

  f32x4 zero4 = {0.f, 0.f, 0.f, 0.f};
  f32x4 oacc[4];
#pragma unroll
  for (int nf = 0; nf < 4; nf++) oacc[nf] = zero4;
  float mrun[4], lrun[4];
#pragma unroll
  for (int r = 0; r < 4; r++) { mrun[r] = -1e30f; lrun[r] = 0.f; }

  for (int kt = 0; kt <= qt; ++kt) {
    int kv0 = kt * 64;
    __syncthreads();
#pragma unroll
    for (int i = 0; i < 2; i++) {
      int sid = i * 256 + tid;
      int r = sid >> 3;
      int sl = slot ^ (r & 7);
      size_t src = (size_t)(kv0 + r) * HD + sl * 8;
      int dst = (i * 256 + wid * 64) * 8;
      gload_lds16(Kh + src, &KtH[dst]);
      gload_lds16(Kl + src, &KtL[dst]);
    }
    uint4 vldH[2], vldL[2];
#pragma unroll
    for (int i = 0; i < 2; i++) {
      int kv = i * 32 + (tid >> 3);
      vldH[i] = *(const uint4*)(Vh + (size_t)(kv0 + kv) * HD + slot * 8);
      vldL[i] = *(const uint4*)(Vl + (size_t)(kv0 + kv) * HD + slot * 8);
    }
#pragma unroll
    for (int i = 0; i < 2; i++) {
      int kv = i * 32 + (tid >> 3);
      int kvslot = kv >> 3, kvlo = kv & 7;
      const u16* ph = (const u16*)&vldH[i];
      const u16* pl = (const u16*)&vldL[i];
#pragma unroll
      for (int j = 0; j < 8; j++) {
        int d = slot * 8 + j;
        int addr = d * 64 + ((kvslot ^ (d & 7)) << 3) + kvlo;
        VtH[addr] = ph[j];
        VtL[addr] = pl[j];
      }
    }
    __syncthreads();

    f32x4 sacc[4];
#pragma unroll
    for (int nf = 0; nf < 4; nf++) sacc[nf] = zero4;
#pragma unroll
    for (int kk = 0; kk < 2; kk++) {
#pragma unroll
      for (int nf = 0; nf < 4; nf++) {
        int krow = nf * 16 + l15;
        int ka = krow * 64 + (((kk * 4 + l4) ^ (krow & 7)) << 3);
        bf16x8 kfh = lds_frag(&KtH[ka]);
        bf16x8 kfl = lds_frag(&KtL[ka]);
        sacc[nf] = mfma16(qfh[kk], kfh, sacc[nf]);
        sacc[nf] = mfma16(qfh[kk], kfl, sacc[nf]);
        sacc[nf] = mfma16(qfl[kk], kfh, sacc[nf]);
      }
    }

    bool diag = (kt == qt);
    float tm[4];
#pragma unroll
    for (int r = 0; r < 4; r++) tm[r] = -1e30f;
#pragma unroll
    for (int nf = 0; nf < 4; nf++) {
#pragma unroll
      for (int r = 0; r < 4; r++) {
        float s = sacc[nf][r] * 0.125f;
        if (diag) {
          int qg = qt * 64 + wid * 16 + l4 * 4 + r;
          int kg = kv0 + nf * 16 + l15;
          if (kg > qg) s = -1e30f;
        }
        sacc[nf][r] = s;
        tm[r] = fmaxf(tm[r], s);
      }
    }
#pragma unroll
    for (int mm = 1; mm < 16; mm <<= 1) {
#pragma unroll
      for (int r = 0; r < 4; r++) tm[r] = fmaxf(tm[r], __shfl_xor(tm[r], mm));
    }
    float ts[4];
#pragma unroll
    for (int r = 0; r < 4; r++) {
      float mn = fmaxf(mrun[r], tm[r]);
      float al = __expf(mrun[r] - mn);
      mrun[r] = mn;
      lrun[r] *= al;
#pragma unroll
      for (int nf = 0; nf < 4; nf++) oacc[nf][r] *= al;
      ts[r] = 0.f;
    }
#pragma unroll
    for (int nf = 0; nf < 4; nf++) {
#pragma unroll
      for (int r = 0; r < 4; r++) {
        float p = __expf(sacc[nf][r] - mrun[r]);
        sacc[nf][r] = p;
        ts[r] += p;
      }
    }
#pragma unroll
    for (int mm = 1; mm < 16; mm <<= 1) {
#pragma unroll
      for (int r = 0; r < 4; r++) ts[r] += __shfl_xor(ts[r], mm);
    }
#pragma unroll
    for (int r = 0; r < 4; r++) lrun[r] += ts[r];

#pragma unroll
    for (int nf = 0; nf < 4; nf++) {
#pragma unroll
      for (int r = 0; r < 4; r++) {
        int qrl = l4 * 4 + r;
        int kv = nf * 16 + l15;
        int addr = qrl * 64 + (((kv >> 3) ^ (qrl & 7)) << 3) + (kv & 7);
        u16 hh, ll;
        split2(sacc[nf][r], hh, ll);
        PtH[wid][addr] = hh;
        PtL[wid][addr] = ll;
      }
    }
#pragma unroll
    for (int s2 = 0; s2 < 2; s2++) {
      int cs = s2 * 4 + l4;
      int pa = l15 * 64 + ((cs ^ (l15 & 7)) << 3);
      bf16x8 pfh = lds_frag(&PtH[wid][pa]);
      bf16x8 pfl = lds_frag(&PtL[wid][pa]);
#pragma unroll
      for (int nf = 0; nf < 4; nf++) {
        int d = nf * 16 + l15;
        int va = d * 64 + ((cs ^ (d & 7)) << 3);
        bf16x8 vfh = lds_frag(&VtH[va]);
        bf16x8 vfl = lds_frag(&VtL[va]);
        oacc[nf] = mfma16(pfh, vfh, oacc[nf]);
        oacc[nf] = mfma16(pfh, vfl, oacc[nf]);
        oacc[nf] = mfma16(pfl, vfh, oacc[nf]);
      }
    }
  }

#pragma unroll
  for (int r = 0; r < 4; r++) {
    float invl = 1.0f / lrun[r];
    int qg = qt * 64 + wid * 16 + l4 * 4 + r;
    size_t tb = ((size_t)qg * BATCH + b) * HDIM + h * HD;
#pragma unroll
    for (int nf = 0; nf < 4; nf++) {
      u16 hh, ll;
      split2(oacc[nf][r] * invl, hh, ll);
      Oh_[tb + nf * 16 + l15] = hh;
      Ol_[tb + nf * 16 + l15] = ll;
    }
  }
}

// ---------------- router: logits, softmax, top-2, counts ----------------
__global__ __launch_bounds__(256)
void router_kernel(const float* __restrict__ x, const float* __restrict__ rw,
                   int* __restrict__ tidx, float* __restrict__ tp, int* __restrict__ cnt) {
  int t = blockIdx.x, tid = threadIdx.x;
  int wid = tid >> 6, lane = tid & 63;
  float4 xv = ((const float4*)(x + (size_t)t * HDIM))[tid];
  __shared__ float part[8][4];
  __shared__ float lg[8];
#pragma unroll
  for (int e = 0; e < 8; e++) {
    float4 wv = ((const float4*)(rw + (size_t)e * HDIM))[tid];
    float d = xv.x * wv.x + xv.y * wv.y + xv.z * wv.z + xv.w * wv.w;
#pragma unroll
    for (int mm = 32; mm >= 1; mm >>= 1) d += __shfl_xor(d, mm);
    if (lane == 0) part[e][wid] = d;
  }
  __syncthreads();
  if (tid < 8) lg[tid] = part[tid][0] + part[tid][1] + part[tid][2] + part[tid][3];
  __syncthreads();
  if (tid == 0) {
    float mx = lg[0];
#pragma unroll
    for (int e = 1; e < 8; e++) mx = fmaxf(mx, lg[e]);
    float g[8]; float se = 0.f;
#pragma unroll
    for (int e = 0; e < 8; e++) { g[e] = __expf(lg[e] - mx); se += g[e]; }
    float inv = 1.0f / se;
#pragma unroll
    for (int e = 0; e < 8; e++) g[e] *= inv;
    int i0 = 0; float v0 = g[0];
#pragma unroll
    for (int e = 1; e < 8; e++) if (g[e] > v0) { v0 = g[e]; i0 = e; }
    int i1 = -1; float v1 = -1.f;
#pragma unroll
    for (int e = 0; e < 8; e++) if (e != i0 && g[e] > v1) { v1 = g[e]; i1 = e; }
    tidx[t * 2] = i0; tidx[t * 2 + 1] = i1;
    tp[t * 2] = v0; tp[t * 2 + 1] = v1;
    atomicAdd(&cnt[i0], 1);
    atomicAdd(&cnt[i1], 1);
  }
}

__global__ void offsets_kernel(const int* __restrict__ cnt, int* __restrict__ off,
                               int* __restrict__ cur) {
  if (threadIdx.x == 0) {
    int a = 0;
    for (int e = 0; e < 8; e++) { off[e] = a; a += cnt[e]; }
    off[8] = a;
  }
  if (threadIdx.x < 8) cur[threadIdx.x] = 0;
}

__global__ __launch_bounds__(256)
void assign_kernel(const int* __restrict__ tidx, const float* __restrict__ tp,
                   const int* __restrict__ off, int* __restrict__ cur,
                   int* __restrict__ rowsIdx, float* __restrict__ wvals,
                   int* __restrict__ inv) {
  int t = blockIdx.x * blockDim.x + threadIdx.x;
  if (t >= TTOK) return;
#pragma unroll
  for (int k = 0; k < 2; k++) {
    int e = tidx[t * 2 + k];
    int s = atomicAdd(&cur[e], 1);
    int pos = off[e] + s;
    rowsIdx[pos] = t;
    wvals[pos] = tp[t * 2 + k];
    inv[t * 2 + k] = pos;
  }
}

__global__ __launch_bounds__(256)
void combine_kernel(float* __restrict__ out, const float* __restrict__ eo,
                    const int* __restrict__ inv) {
  int t = blockIdx.x, c = threadIdx.x;
  int r0 = inv[t * 2], r1 = inv[t * 2 + 1];
  float4* o = (float4*)(out + (size_t)t * HDIM);
  const float4* e0 = (const float4*)(eo + (size_t)r0 * HDIM);
  const float4* e1 = (const float4*)(eo + (size_t)r1 * HDIM);
  float4 v = o[c];
  float4 a = e0[c];
  float4 bb = e1[c];
  v.x += a.x + bb.x; v.y += a.y + bb.y; v.z += a.z + bb.z; v.w += a.w + bb.w;
  o[c] = v;
}

extern "C" void kernel_launch(void* const* d_in, const int* in_sizes, int n_in,
                              void* d_out, int out_size, void* d_ws, size_t ws_size,
                              hipStream_t stream) {
  (void)in_sizes; (void)n_in; (void)out_size; (void)ws_size;
  const float* hs    = (const float*)d_in[0];
  const float* ln1w  = (const float*)d_in[1];
  const float* ln1b  = (const float*)d_in[2];
  const float* ln2w  = (const float*)d_in[3];
  const float* ln2b  = (const float*)d_in[4];
  const float* wqkv  = (const float*)d_in[5];
  const float* wproj = (const float*)d_in[6];
  const float* wrout = (const float*)d_in[7];
  const float* w1    = (const float*)d_in[8];
  const float* w2    = (const float*)d_in[9];
  float* out = (float*)d_out;

  char* p = (char*)d_ws;
  auto alloc = [&](size_t n) { void* r = (void*)p; p += (n + 255) & ~(size_t)255; return r; };
  u16* wqkv_h  = (u16*)alloc((size_t)QKVO * HDIM * 2);
  u16* wqkv_l  = (u16*)alloc((size_t)QKVO * HDIM * 2);
  u16* wproj_h = (u16*)alloc((size_t)HDIM * HDIM * 2);
  u16* wproj_l = (u16*)alloc((size_t)HDIM * HDIM * 2);
  u16* w1t     = (u16*)alloc((size_t)NEXP * FDIM * HDIM * 2);
  u16* w2t     = (u16*)alloc((size_t)NEXP * HDIM * FDIM * 2);
  u16* ln1h    = (u16*)alloc((size_t)TTOK * HDIM * 2);
  u16* ln1l    = (u16*)alloc((size_t)TTOK * HDIM * 2);
  u16* Qbh     = (u16*)alloc((size_t)BATCH * NHEADS * SLEN * HD * 2);
  u16* Qbl     = (u16*)alloc((size_t)BATCH * NHEADS * SLEN * HD * 2);
  u16* Kbh     = (u16*)alloc((size_t)BATCH * NKV * SLEN * HD * 2);
  u16* Kbl     = (u16*)alloc((size_t)BATCH * NKV * SLEN * HD * 2);
  u16* Vbh     = (u16*)alloc((size_t)BATCH * NKV * SLEN * HD * 2);
  u16* Vbl     = (u16*)alloc((size_t)BATCH * NKV * SLEN * HD * 2);
  u16* attn_h  = (u16*)alloc((size_t)TTOK * HDIM * 2);
  u16* attn_l  = (u16*)alloc((size_t)TTOK * HDIM * 2);
  u16* ln2o    = (u16*)alloc((size_t)TTOK * HDIM * 2);
  float* ln2f  = (float*)alloc((size_t)TTOK * HDIM * 4);
  // hmid region doubles as qkvC fp32 scratch (disjoint liveness)
  char* hmid_region = (char*)alloc((size_t)TTOK * 2 * FDIM * 2);
  u16* hmid    = (u16*)hmid_region;
  float* qkvC  = (float*)hmid_region;  // 4096*1536*4 = 25MB <= 32MB
  float* eo    = (float*)alloc((size_t)TTOK * 2 * HDIM * 4);
  int* tidx    = (int*)alloc(TTOK * 2 * 4);
  float* tp    = (float*)alloc(TTOK * 2 * 4);
  int* rowsIdx = (int*)alloc(TTOK * 2 * 4);
  float* wvals = (float*)alloc(TTOK * 2 * 4);
  int* invm    = (int*)alloc(TTOK * 2 * 4);
  int* cnt     = (int*)alloc(8 * 4);
  int* offs    = (int*)alloc(9 * 4);
  int* cur     = (int*)alloc(8 * 4);

  hipMemsetAsync(cnt, 0, 8 * 4, stream);

  {
    int n4 = QKVO * HDIM / 4;
    cvt_split_kernel<<<(n4 + 255) / 256, 256, 0, stream>>>(wqkv, wqkv_h, wqkv_l, n4);
  }
  {
    int n4 = HDIM * HDIM / 4;
    cvt_split_kernel<<<(n4 + 255) / 256, 256, 0, stream>>>(wproj, wproj_h, wproj_l, n4);
  }
  dim3 tb(32, 8);
  transpose_cvt_kernel<<<dim3(FDIM / 32, HDIM / 32, NEXP), tb, 0, stream>>>(w1, w1t, HDIM, FDIM);
  transpose_cvt_kernel<<<dim3(HDIM / 32, FDIM / 32, NEXP), tb, 0, stream>>>(w2, w2t, FDIM, HDIM);

  ln_kernel<<<TTOK, 256, 0, stream>>>(hs, ln1w, ln1b, ln1h, ln1l, nullptr);

  gemm_split<0><<<dim3(QKVO / 128, TTOK / 128), 256, 0, stream>>>(
      ln1h, ln1l, wqkv_h, wqkv_l, TTOK, QKVO, HDIM, nullptr, qkvC);

  qkv_scatter<<<dim3(QKVO / 256, TTOK), 256, 0, stream>>>(qkvC, Qbh, Qbl, Kbh, Kbl, Vbh, Vbl);

  attn_kernel<<<dim3(SLEN / 64, BATCH * NHEADS), 256, 0, stream>>>(
      Qbh, Qbl, Kbh, Kbl, Vbh, Vbl, attn_h, attn_l);

  gemm_split<1><<<dim3(HDIM / 128, TTOK / 128), 256, 0, stream>>>(
      attn_h, attn_l, wproj_h, wproj_l, TTOK, HDIM, HDIM, hs, out);

  ln_kernel<<<TTOK, 256, 0, stream>>>(out, ln2w, ln2b, ln2o, nullptr, ln2f);

  router_kernel<<<TTOK, 256, 0, stream>>>(ln2f, wrout, tidx, tp, cnt);
  offsets_kernel<<<1, 64, 0, stream>>>(cnt, offs, cur);
  assign_kernel<<<TTOK / 256, 256, 0, stream>>>(tidx, tp, offs, cur, rowsIdx, wvals, invm);

  gemm_moe<2><<<dim3(FDIM / 128, TTOK / 128, NEXP), 256, 0, stream>>>(
      ln2o, w1t, FDIM, HDIM, nullptr, hmid, offs, rowsIdx, nullptr);

  gemm_moe<3><<<dim3(HDIM / 128, TTOK / 128, NEXP), 256, 0, stream>>>(
      hmid, w2t, HDIM, FDIM, eo, nullptr, offs, nullptr, wvals);

  combine_kernel<<<TTOK, 256, 0, stream>>>(out, eo, invm);
}

// Round 3
// 599.582 us; speedup vs baseline: 1.1526x; 1.1526x over previous
//
#include <hip/hip_runtime.h>
#include <stdint.h>

typedef unsigned short u16;
typedef float f32x4 __attribute__((ext_vector_type(4)));
typedef __bf16 bf16x8 __attribute__((ext_vector_type(8)));
typedef u16 u16x8 __attribute__((ext_vector_type(8)));

#define NHEADS 16
#define NKV 4
#define HD 64
#define HDIM 1024
#define FDIM 2048
#define SLEN 1024
#define BATCH 4
#define TTOK 4096
#define NEXP 8
#define QKVO 1536
#define K3 3072

__device__ __forceinline__ u16 f2bf(float f) {
  union { float f; uint32_t u; } c; c.f = f;
  uint32_t u = c.u;
  return (u16)((u + 0x7FFFu + ((u >> 16) & 1u)) >> 16);
}
__device__ __forceinline__ float bf2f(u16 h) {
  union { uint32_t u; float f; } c; c.u = ((uint32_t)h) << 16; return c.f;
}
__device__ __forceinline__ void split2(float v, u16& h, u16& l) {
  h = f2bf(v);
  l = f2bf(v - bf2f(h));
}

__device__ __forceinline__ f32x4 mfma16(bf16x8 a, bf16x8 b, f32x4 c) {
  return __builtin_amdgcn_mfma_f32_16x16x32_bf16(a, b, c, 0, 0, 0);
}

__device__ __forceinline__ bf16x8 lds_frag(const u16* base) {
  u16x8 v = *(const u16x8*)base;
  return __builtin_bit_cast(bf16x8, v);
}

__device__ __forceinline__ void gload_lds16(const void* g, void* l) {
  __builtin_amdgcn_global_load_lds((const __attribute__((address_space(1))) void*)g,
                                   (__attribute__((address_space(3))) void*)l, 16, 0, 0);
}

// ---- fp32 weight [R][1024] -> 3-wide split bf16 [R][3072] = [hi|hi|lo] ----
__global__ __launch_bounds__(256)
void cvt_w3_kernel(const float* __restrict__ in, u16* __restrict__ out, int n4) {
  int i = blockIdx.x * blockDim.x + threadIdx.x;
  if (i >= n4) return;
  float4 v = ((const float4*)in)[i];
  int row = i >> 8;        // 256 float4 per 1024-wide row
  int c = (i & 255) * 4;
  ushort4 h, l;
  split2(v.x, h.x, l.x); split2(v.y, h.y, l.y);
  split2(v.z, h.z, l.z); split2(v.w, h.w, l.w);
  u16* orow = out + (size_t)row * K3 + c;
  *(ushort4*)(orow) = h;
  *(ushort4*)(orow + 1024) = h;
  *(ushort4*)(orow + 2048) = l;
}

// ---- tiled transpose + convert: in [R][C] f32 -> out [C][R] bf16, z = expert ----
__global__ __launch_bounds__(256)
void transpose_cvt_kernel(const float* __restrict__ in, u16* __restrict__ out, int R, int C) {
  __shared__ float tile[32][33];
  size_t eoff = (size_t)blockIdx.z * (size_t)R * (size_t)C;
  in += eoff; out += eoff;
  int c0 = blockIdx.x * 32, r0 = blockIdx.y * 32;
  int tx = threadIdx.x, ty = threadIdx.y;
#pragma unroll
  for (int i = 0; i < 4; i++)
    tile[ty + i * 8][tx] = in[(size_t)(r0 + ty + i * 8) * C + c0 + tx];
  __syncthreads();
#pragma unroll
  for (int i = 0; i < 4; i++)
    out[(size_t)(c0 + ty + i * 8) * R + r0 + tx] = f2bf(tile[tx][ty + i * 8]);
}

// ---- LayerNorm: o3 (3-wide [hi|lo|hi]) OR (obf single + of32) ----
__global__ __launch_bounds__(256)
void ln_kernel(const float* __restrict__ x, const float* __restrict__ w,
               const float* __restrict__ bias, u16* __restrict__ o3,
               u16* __restrict__ obf, float* __restrict__ of32) {
  int t = blockIdx.x, tid = threadIdx.x;
  int wid = tid >> 6, lane = tid & 63;
  float4 v = ((const float4*)(x + (size_t)t * HDIM))[tid];
  float s = v.x + v.y + v.z + v.w;
  float q = v.x * v.x + v.y * v.y + v.z * v.z + v.w * v.w;
#pragma unroll
  for (int mm = 32; mm >= 1; mm >>= 1) {
    s += __shfl_xor(s, mm);
    q += __shfl_xor(q, mm);
  }
  __shared__ float ss[4], qq[4];
  if (lane == 0) { ss[wid] = s; qq[wid] = q; }
  __syncthreads();
  s = ss[0] + ss[1] + ss[2] + ss[3];
  q = qq[0] + qq[1] + qq[2] + qq[3];
  float mu = s * (1.0f / HDIM);
  float var = q * (1.0f / HDIM) - mu * mu;
  float inv = rsqrtf(var + 1e-5f);
  float4 wv = ((const float4*)w)[tid];
  float4 bv = ((const float4*)bias)[tid];
  float y0 = (v.x - mu) * inv * wv.x + bv.x;
  float y1 = (v.y - mu) * inv * wv.y + bv.y;
  float y2 = (v.z - mu) * inv * wv.z + bv.z;
  float y3 = (v.w - mu) * inv * wv.w + bv.w;
  ushort4 h, l;
  split2(y0, h.x, l.x); split2(y1, h.y, l.y);
  split2(y2, h.z, l.z); split2(y3, h.w, l.w);
  if (o3) {
    u16* orow = o3 + (size_t)t * K3 + tid * 4;
    *(ushort4*)(orow) = h;
    *(ushort4*)(orow + 1024) = l;
    *(ushort4*)(orow + 2048) = h;
  }
  if (obf) ((ushort4*)(obf + (size_t)t * HDIM))[tid] = h;
  if (of32) {
    float4 yo; yo.x = y0; yo.y = y1; yo.z = y2; yo.w = y3;
    ((float4*)(of32 + (size_t)t * HDIM))[tid] = yo;
  }
}

// ---- GEMM C[M,N] = A[M,K] * B[N,K]^T, bf16, dbuf, gload_lds ----
// MODE 0: QKV (K=3072 interleaved-split) -> split2 scatter to Q/K/V hi+lo
// MODE 1: proj (K=3072) -> outf = C + resid
// MODE 2: moe w1 (grouped, gathered rows) -> gelu -> o0 bf16
// MODE 3: moe w2 (grouped, contiguous)    -> outf = C * wts
template<int MODE>
__global__ __launch_bounds__(256)
void gemm_bt(const u16* __restrict__ A0, const u16* __restrict__ B0,
             int N, int K, int M,
             const float* __restrict__ resid, float* __restrict__ outf,
             u16* __restrict__ o0, u16* __restrict__ o1, u16* __restrict__ o2,
             u16* __restrict__ o3, u16* __restrict__ o4, u16* __restrict__ o5,
             const int* __restrict__ offs, const int* __restrict__ rowsIdx,
             const float* __restrict__ wts) {
  int tid = threadIdx.x;
  int wid = tid >> 6, lane = tid & 63;
  int l15 = lane & 15, l4 = lane >> 4;
  int bn = blockIdx.x, bm = blockIdx.y, e = blockIdx.z;

  int Me = M, rowBase = 0;
  const u16* A = A0;
  const u16* B = B0;
  if constexpr (MODE == 2 || MODE == 3) {
    int oa = offs[e], ob = offs[e + 1];
    Me = ob - oa; rowBase = oa;
    B = B0 + (size_t)e * (size_t)N * (size_t)K;
    if constexpr (MODE == 3) A = A0 + (size_t)oa * (size_t)K;
  }
  if (bm * 128 >= Me) return;

  __shared__ u16 lsA[2][128 * 64];
  __shared__ u16 lsB[2][128 * 64];

  int slot = tid & 7;
  const u16* aPtr[4];
  const u16* bPtr[4];
#pragma unroll
  for (int i = 0; i < 4; i++) {
    int r = i * 32 + (tid >> 3);
    int sl = slot ^ (r & 7);
    int rg = bm * 128 + r;
    if constexpr (MODE == 2) {
      int rc = rg < Me ? rg : (Me - 1);
      rg = rowsIdx[rowBase + rc];
    } else if constexpr (MODE == 3) {
      rg = rg < Me ? rg : (Me - 1);
    }
    aPtr[i] = A + (size_t)rg * K + sl * 8;
    int ng = bn * 128 + r;
    bPtr[i] = B + (size_t)ng * K + sl * 8;
  }

  int wm = (wid >> 1) * 64, wn = (wid & 1) * 64;
  f32x4 zero4 = {0.f, 0.f, 0.f, 0.f};
  f32x4 acc[4][4];
#pragma unroll
  for (int mi = 0; mi < 4; mi++)
#pragma unroll
    for (int ni = 0; ni < 4; ni++) acc[mi][ni] = zero4;

  int aoff[4][2], boff[4][2];
#pragma unroll
  for (int mi = 0; mi < 4; mi++) {
    int row = wm + mi * 16 + l15;
#pragma unroll
    for (int kk = 0; kk < 2; kk++) {
      int cs = kk * 4 + l4;
      aoff[mi][kk] = row * 64 + ((cs ^ (row & 7)) << 3);
    }
  }
#pragma unroll
  for (int ni = 0; ni < 4; ni++) {
    int row = wn + ni * 16 + l15;
#pragma unroll
    for (int kk = 0; kk < 2; kk++) {
      int cs = kk * 4 + l4;
      boff[ni][kk] = row * 64 + ((cs ^ (row & 7)) << 3);
    }
  }

  int nk = K >> 6;
#pragma unroll
  for (int i = 0; i < 4; i++) {
    gload_lds16(aPtr[i], &lsA[0][(i * 256 + wid * 64) * 8]);
    gload_lds16(bPtr[i], &lsB[0][(i * 256 + wid * 64) * 8]);
  }
  __syncthreads();

  int buf = 0;
  for (int kt = 0; kt < nk; ++kt) {
    if (kt + 1 < nk) {
      int k0 = (kt + 1) << 6;
#pragma unroll
      for (int i = 0; i < 4; i++) {
        gload_lds16(aPtr[i] + k0, &lsA[buf ^ 1][(i * 256 + wid * 64) * 8]);
        gload_lds16(bPtr[i] + k0, &lsB[buf ^ 1][(i * 256 + wid * 64) * 8]);
      }
    }
#pragma unroll
    for (int kk = 0; kk < 2; kk++) {
      bf16x8 af[4], bfr[4];
#pragma unroll
      for (int mi = 0; mi < 4; mi++) af[mi] = lds_frag(&lsA[buf][aoff[mi][kk]]);
#pragma unroll
      for (int ni = 0; ni < 4; ni++) bfr[ni] = lds_frag(&lsB[buf][boff[ni][kk]]);
#pragma unroll
      for (int mi = 0; mi < 4; mi++)
#pragma unroll
        for (int ni = 0; ni < 4; ni++)
          acc[mi][ni] = mfma16(af[mi], bfr[ni], acc[mi][ni]);
    }
    __syncthreads();
    buf ^= 1;
  }

#pragma unroll
  for (int mi = 0; mi < 4; mi++) {
#pragma unroll
    for (int r = 0; r < 4; r++) {
      int m = bm * 128 + wm + mi * 16 + l4 * 4 + r;
      if (m >= Me) continue;
#pragma unroll
      for (int ni = 0; ni < 4; ni++) {
        int n = bn * 128 + wn + ni * 16 + l15;
        float v = acc[mi][ni][r];
        if constexpr (MODE == 0) {
          u16 hh, ll; split2(v, hh, ll);
          int sq = m >> 2, bb = m & 3;
          int d = n & 63;
          if (n < 1024) {
            int hd = n >> 6;
            size_t o = ((size_t)(bb * NHEADS + hd) * SLEN + sq) * HD + d;
            o0[o] = hh; o1[o] = ll;
          } else if (n < 1280) {
            int hd = (n - 1024) >> 6;
            size_t o = ((size_t)(bb * NKV + hd) * SLEN + sq) * HD + d;
            o2[o] = hh; o3[o] = ll;
          } else {
            int hd = (n - 1280) >> 6;
            size_t o = ((size_t)(bb * NKV + hd) * SLEN + sq) * HD + d;
            o4[o] = hh; o5[o] = ll;
          }
        } else if constexpr (MODE == 1) {
          size_t idx = (size_t)m * HDIM + n;
          outf[idx] = v + resid[idx];
        } else if constexpr (MODE == 2) {
          float g = 0.5f * v * (1.0f + tanhf(0.7978845608f * (v + 0.044715f * v * v * v)));
          o0[(size_t)(rowBase + m) * FDIM + n] = f2bf(g);
        } else {
          outf[(size_t)(rowBase + m) * HDIM + n] = v * wts[rowBase + m];
        }
      }
    }
  }
}

// ---- flash attention, causal, GQA, split precision, dbuf-K, prefetch-V ----
__global__ __launch_bounds__(256)
void attn_kernel(const u16* __restrict__ Qh_, const u16* __restrict__ Ql_,
                 const u16* __restrict__ Kh_, const u16* __restrict__ Kl_,
                 const u16* __restrict__ Vh_, const u16* __restrict__ Vl_,
                 u16* __restrict__ A3) {
  int bh = blockIdx.x;   // fast dim = bh for CU load balance across qt
  int qt = blockIdx.y;
  int b = bh >> 4, h = bh & 15, kh = h >> 2;
  int tid = threadIdx.x, wid = tid >> 6, lane = tid & 63;
  int l15 = lane & 15, l4 = lane >> 4;
  int slot = tid & 7;

  size_t qoff = ((size_t)(b * NHEADS + h) * SLEN) * HD;
  size_t koff = ((size_t)(b * NKV + kh) * SLEN) * HD;
  const u16* Qh = Qh_ + qoff;
  const u16* Ql = Ql_ + qoff;
  const u16* Kh = Kh_ + koff;
  const u16* Kl = Kl_ + koff;
  const u16* Vh = Vh_ + koff;
  const u16* Vl = Vl_ + koff;

  __shared__ u16 KtH[2][4096], KtL[2][4096];
  __shared__ u16 VtH[4096], VtL[4096];
  __shared__ u16 PtH[4][1024], PtL[4][1024];

  int qrow = qt * 64 + wid * 16 + l15;
  bf16x8 qfh[2], qfl[2];
#pragma unroll
  for (int kk = 0; kk < 2; kk++) {
    u16x8 vh = *(const u16x8*)(Qh + (size_t)qrow * HD + kk * 32 + l4 * 8);
    u16x8 vl = *(const u16x8*)(Ql + (size_t)qrow * HD + kk * 32 + l4 * 8);
    qfh[kk] = __builtin_bit_cast(bf16x8, vh);
    qfl[kk] = __builtin_bit_cast(bf16x8, vl);
  }

  // --- staging helpers (inline) ---
  int kr0 = tid >> 3;            // 0..31
  int kr1 = 32 + (tid >> 3);
  int sl0 = slot ^ (kr0 & 7);
  int sl1 = slot ^ (kr1 & 7);
  int kdst0 = (0 * 256 + wid * 64) * 8;
  int kdst1 = (1 * 256 + wid * 64) * 8;

#define STAGE_K(kt_, bf_)                                                     \
  {                                                                           \
    size_t s0 = (size_t)((kt_)*64 + kr0) * HD + sl0 * 8;                      \
    size_t s1 = (size_t)((kt_)*64 + kr1) * HD + sl1 * 8;                      \
    gload_lds16(Kh + s0, &KtH[bf_][kdst0]);                                   \
    gload_lds16(Kl + s0, &KtL[bf_][kdst0]);                                   \
    gload_lds16(Kh + s1, &KtH[bf_][kdst1]);                                   \
    gload_lds16(Kl + s1, &KtL[bf_][kdst1]);                                   \
  }

#define LOAD_V(kt_, vh_, vl_)                                                 \
  {                                                                           \
    _Pragma("unroll") for (int i = 0; i < 2; i++) {                           \
      int kv = i * 32 + (tid >> 3);                                           \
      (vh_)[i] = *(const uint4*)(Vh + (size_t)((kt_)*64 + kv) * HD + slot * 8);\
      (vl_)[i] = *(const uint4*)(Vl + (size_t)((kt_)*64 + kv) * HD + slot * 8);\
    }                                                                         \
  }

#define SCATTER_V(vh_, vl_)                                                   \
  {                                                                           \
    _Pragma("unroll") for (int i = 0; i < 2; i++) {                           \
      int kv = i * 32 + (tid >> 3);                                           \
      const u16* ph = (const u16*)&(vh_)[i];                                  \
      const u16* pl = (const u16*)&(vl_)[i];                                  \
      _Pragma("unroll") for (int j = 0; j < 8; j++) {                         \
        int d = slot * 8 + j;                                                 \
        int g = ((kv >> 3) ^ (d & 7) ^ (d >> 3)) & 7;                         \
        int addr = d * 64 + (g << 3) + (kv & 7);                              \
        VtH[addr] = ph[j];                                                    \
        VtL[addr] = pl[j];                                                    \
      }                                                                       \
    }                                                                         \
  }

  uint4 vH[2], vL[2];
  STAGE_K(0, 0);
  LOAD_V(0, vH, vL);
  SCATTER_V(vH, vL);
  __syncthreads();   // drains vmcnt: K(0) staged; Vt visible

  f32x4 zero4 = {0.f, 0.f, 0.f, 0.f};
  f32x4 oacc[4];
#pragma unroll
  for (int nf = 0; nf < 4; nf++) oacc[nf] = zero4;
  float mrun[4], lrun[4];
#pragma unroll
  for (int r = 0; r < 4; r++) { mrun[r] = -1e30f; lrun[r] = 0.f; }

  int buf = 0;
  for (int kt = 0; kt <= qt; ++kt) {
    int kv0 = kt * 64;
    // prefetch next tile while computing current
    if (kt < qt) {
      STAGE_K(kt + 1, buf ^ 1);
      LOAD_V(kt + 1, vH, vL);
    }

    // QK^T (3-term split)
    f32x4 sacc[4];
#pragma unroll
    for (int nf = 0; nf < 4; nf++) sacc[nf] = zero4;
#pragma unroll
    for (int kk = 0; kk < 2; kk++) {
#pragma unroll
      for (int nf = 0; nf < 4; nf++) {
        int krow = nf * 16 + l15;
        int ka = krow * 64 + (((kk * 4 + l4) ^ (krow & 7)) << 3);
        bf16x8 kfh = lds_frag(&KtH[buf][ka]);
        bf16x8 kfl = lds_frag(&KtL[buf][ka]);
        sacc[nf] = mfma16(qfh[kk], kfh, sacc[nf]);
        sacc[nf] = mfma16(qfh[kk], kfl, sacc[nf]);
        sacc[nf] = mfma16(qfl[kk], kfh, sacc[nf]);
      }
    }

    bool diag = (kt == qt);
    float tm[4];
#pragma unroll
    for (int r = 0; r < 4; r++) tm[r] = -1e30f;
#pragma unroll
    for (int nf = 0; nf < 4; nf++) {
#pragma unroll
      for (int r = 0; r < 4; r++) {
        float s = sacc[nf][r] * 0.125f;
        if (diag) {
          int qg = qt * 64 + wid * 16 + l4 * 4 + r;
          int kg = kv0 + nf * 16 + l15;
          if (kg > qg) s = -1e30f;
        }
        sacc[nf][r] = s;
        tm[r] = fmaxf(tm[r], s);
      }
    }
#pragma unroll
    for (int mm = 1; mm < 16; mm <<= 1) {
#pragma unroll
      for (int r = 0; r < 4; r++) tm[r] = fmaxf(tm[r], __shfl_xor(tm[r], mm));
    }
    float ts[4];
#pragma unroll
    for (int r = 0; r < 4; r++) {
      float mn = fmaxf(mrun[r], tm[r]);
      float al = __expf(mrun[r] - mn);
      mrun[r] = mn;
      lrun[r] *= al;
#pragma unroll
      for (int nf = 0; nf < 4; nf++) oacc[nf][r] *= al;
      ts[r] = 0.f;
    }
#pragma unroll
    for (int nf = 0; nf < 4; nf++) {
#pragma unroll
      for (int r = 0; r < 4; r++) {
        float p = __expf(sacc[nf][r] - mrun[r]);
        sacc[nf][r] = p;
        ts[r] += p;
      }
    }
#pragma unroll
    for (int mm = 1; mm < 16; mm <<= 1) {
#pragma unroll
      for (int r = 0; r < 4; r++) ts[r] += __shfl_xor(ts[r], mm);
    }
#pragma unroll
    for (int r = 0; r < 4; r++) lrun[r] += ts[r];

    // P -> per-wave LDS (swizzled, conflict-spread by row>>3)
#pragma unroll
    for (int nf = 0; nf < 4; nf++) {
#pragma unroll
      for (int r = 0; r < 4; r++) {
        int qrl = l4 * 4 + r;
        int kv = nf * 16 + l15;
        int g = ((kv >> 3) ^ (qrl & 7) ^ (qrl >> 3)) & 7;
        int addr = qrl * 64 + (g << 3) + (kv & 7);
        u16 hh, ll;
        split2(sacc[nf][r], hh, ll);
        PtH[wid][addr] = hh;
        PtL[wid][addr] = ll;
      }
    }
    // PV (3-term split)
#pragma unroll
    for (int s2 = 0; s2 < 2; s2++) {
      int cs = s2 * 4 + l4;
      int pa = l15 * 64 + ((((cs ^ (l15 & 7) ^ (l15 >> 3))) & 7) << 3);
      bf16x8 pfh = lds_frag(&PtH[wid][pa]);
      bf16x8 pfl = lds_frag(&PtL[wid][pa]);
#pragma unroll
      for (int nf = 0; nf < 4; nf++) {
        int d = nf * 16 + l15;
        int va = d * 64 + ((((cs ^ (d & 7) ^ (d >> 3))) & 7) << 3);
        bf16x8 vfh = lds_frag(&VtH[va]);
        bf16x8 vfl = lds_frag(&VtL[va]);
        oacc[nf] = mfma16(pfh, vfh, oacc[nf]);
        oacc[nf] = mfma16(pfh, vfl, oacc[nf]);
        oacc[nf] = mfma16(pfl, vfh, oacc[nf]);
      }
    }

    __syncthreads();   // drains vmcnt: K(kt+1)/V(kt+1) arrived; Vt free
    if (kt < qt) {
      SCATTER_V(vH, vL);
    }
    __syncthreads();   // Vt(kt+1) visible
    buf ^= 1;
  }

  // epilogue: write attn_3 row = [hi | lo | hi]
#pragma unroll
  for (int r = 0; r < 4; r++) {
    float invl = 1.0f / lrun[r];
    int qg = qt * 64 + wid * 16 + l4 * 4 + r;
    size_t tb = ((size_t)qg * BATCH + b) * K3 + h * HD;
#pragma unroll
    for (int nf = 0; nf < 4; nf++) {
      u16 hh, ll;
      split2(oacc[nf][r] * invl, hh, ll);
      size_t o = tb + nf * 16 + l15;
      A3[o] = hh;
      A3[o + 1024] = ll;
      A3[o + 2048] = hh;
    }
  }
#undef STAGE_K
#undef LOAD_V
#undef SCATTER_V
}

// ---- router: logits, softmax, top-2, counts ----
__global__ __launch_bounds__(256)
void router_kernel(const float* __restrict__ x, const float* __restrict__ rw,
                   int* __restrict__ tidx, float* __restrict__ tp, int* __restrict__ cnt) {
  int t = blockIdx.x, tid = threadIdx.x;
  int wid = tid >> 6, lane = tid & 63;
  float4 xv = ((const float4*)(x + (size_t)t * HDIM))[tid];
  __shared__ float part[8][4];
  __shared__ float lg[8];
#pragma unroll
  for (int e = 0; e < 8; e++) {
    float4 wv = ((const float4*)(rw + (size_t)e * HDIM))[tid];
    float d = xv.x * wv.x + xv.y * wv.y + xv.z * wv.z + xv.w * wv.w;
#pragma unroll
    for (int mm = 32; mm >= 1; mm >>= 1) d += __shfl_xor(d, mm);
    if (lane == 0) part[e][wid] = d;
  }
  __syncthreads();
  if (tid < 8) lg[tid] = part[tid][0] + part[tid][1] + part[tid][2] + part[tid][3];
  __syncthreads();
  if (tid == 0) {
    float mx = lg[0];
#pragma unroll
    for (int e = 1; e < 8; e++) mx = fmaxf(mx, lg[e]);
    float g[8]; float se = 0.f;
#pragma unroll
    for (int e = 0; e < 8; e++) { g[e] = __expf(lg[e] - mx); se += g[e]; }
    float inv = 1.0f / se;
#pragma unroll
    for (int e = 0; e < 8; e++) g[e] *= inv;
    int i0 = 0; float v0 = g[0];
#pragma unroll
    for (int e = 1; e < 8; e++) if (g[e] > v0) { v0 = g[e]; i0 = e; }
    int i1 = -1; float v1 = -1.f;
#pragma unroll
    for (int e = 0; e < 8; e++) if (e != i0 && g[e] > v1) { v1 = g[e]; i1 = e; }
    tidx[t * 2] = i0; tidx[t * 2 + 1] = i1;
    tp[t * 2] = v0; tp[t * 2 + 1] = v1;
    atomicAdd(&cnt[i0], 1);
    atomicAdd(&cnt[i1], 1);
  }
}

__global__ void offsets_kernel(const int* __restrict__ cnt, int* __restrict__ off,
                               int* __restrict__ cur) {
  if (threadIdx.x == 0) {
    int a = 0;
    for (int e = 0; e < 8; e++) { off[e] = a; a += cnt[e]; }
    off[8] = a;
  }
  if (threadIdx.x < 8) cur[threadIdx.x] = 0;
}

__global__ __launch_bounds__(256)
void assign_kernel(const int* __restrict__ tidx, const float* __restrict__ tp,
                   const int* __restrict__ off, int* __restrict__ cur,
                   int* __restrict__ rowsIdx, float* __restrict__ wvals,
                   int* __restrict__ inv) {
  int t = blockIdx.x * blockDim.x + threadIdx.x;
  if (t >= TTOK) return;
#pragma unroll
  for (int k = 0; k < 2; k++) {
    int e = tidx[t * 2 + k];
    int s = atomicAdd(&cur[e], 1);
    int pos = off[e] + s;
    rowsIdx[pos] = t;
    wvals[pos] = tp[t * 2 + k];
    inv[t * 2 + k] = pos;
  }
}

__global__ __launch_bounds__(256)
void combine_kernel(float* __restrict__ out, const float* __restrict__ eo,
                    const int* __restrict__ inv) {
  int t = blockIdx.x, c = threadIdx.x;
  int r0 = inv[t * 2], r1 = inv[t * 2 + 1];
  float4* o = (float4*)(out + (size_t)t * HDIM);
  const float4* e0 = (const float4*)(eo + (size_t)r0 * HDIM);
  const float4* e1 = (const float4*)(eo + (size_t)r1 * HDIM);
  float4 v = o[c];
  float4 a = e0[c];
  float4 bb = e1[c];
  v.x += a.x + bb.x; v.y += a.y + bb.y; v.z += a.z + bb.z; v.w += a.w + bb.w;
  o[c] = v;
}

extern "C" void kernel_launch(void* const* d_in, const int* in_sizes, int n_in,
                              void* d_out, int out_size, void* d_ws, size_t ws_size,
                              hipStream_t stream) {
  (void)in_sizes; (void)n_in; (void)out_size; (void)ws_size;
  const float* hs    = (const float*)d_in[0];
  const float* ln1w  = (const float*)d_in[1];
  const float* ln1b  = (const float*)d_in[2];
  const float* ln2w  = (const float*)d_in[3];
  const float* ln2b  = (const float*)d_in[4];
  const float* wqkv  = (const float*)d_in[5];
  const float* wproj = (const float*)d_in[6];
  const float* wrout = (const float*)d_in[7];
  const float* w1    = (const float*)d_in[8];
  const float* w2    = (const float*)d_in[9];
  float* out = (float*)d_out;

  char* base = (char*)d_ws;
  size_t off = 0;
  auto alloc = [&](size_t n) { void* r = base + off; off += (n + 255) & ~(size_t)255; return r; };

  const size_t SZ_W1T   = (size_t)NEXP * FDIM * HDIM * 2;   // 33.5 MB
  const size_t SZ_W2T   = (size_t)NEXP * HDIM * FDIM * 2;   // 33.5 MB
  const size_t SZ_WP3   = (size_t)HDIM * K3 * 2;            // 6.3 MB
  const size_t SZ_LN13  = (size_t)TTOK * K3 * 2;            // 25.2 MB
  const size_t SZ_WQ3   = (size_t)QKVO * K3 * 2;            // 9.4 MB
  const size_t SZ_HMID  = (size_t)TTOK * 2 * FDIM * 2;      // 33.5 MB
  const size_t SZ_Q     = (size_t)BATCH * NHEADS * SLEN * HD * 2;  // 8.4 MB
  const size_t SZ_KV    = (size_t)BATCH * NKV * SLEN * HD * 2;     // 2.1 MB
  const size_t SZ_A3    = (size_t)TTOK * K3 * 2;            // 25.2 MB
  const size_t SZ_EO    = (size_t)TTOK * 2 * HDIM * 4;      // 33.5 MB

  u16* w1t     = (u16*)alloc(SZ_W1T);
  u16* w2t     = (u16*)alloc(SZ_W2T);
  u16* wproj3  = (u16*)alloc(SZ_WP3);

  // region R1: {ln1_3, wqkv3} (dead after QKV gemm)  overlaid by  hmid
  size_t r1sz = SZ_LN13 + SZ_WQ3;
  if (SZ_HMID > r1sz) r1sz = SZ_HMID;
  char* r1 = (char*)alloc(r1sz);
  u16* ln1_3 = (u16*)r1;
  u16* wqkv3 = (u16*)(r1 + SZ_LN13);
  u16* hmid  = (u16*)r1;

  // region R2: {Q/K/V hi+lo (dead after attn), attn_3 (dead after proj)} overlaid by eo
  size_t r2sz = 2 * SZ_Q + 4 * SZ_KV + SZ_A3;
  if (SZ_EO > r2sz) r2sz = SZ_EO;
  char* r2 = (char*)alloc(r2sz);
  u16* Qbh = (u16*)r2;
  u16* Qbl = (u16*)(r2 + SZ_Q);
  u16* Kbh = (u16*)(r2 + 2 * SZ_Q);
  u16* Kbl = (u16*)(r2 + 2 * SZ_Q + SZ_KV);
  u16* Vbh = (u16*)(r2 + 2 * SZ_Q + 2 * SZ_KV);
  u16* Vbl = (u16*)(r2 + 2 * SZ_Q + 3 * SZ_KV);
  u16* attn3 = (u16*)(r2 + 2 * SZ_Q + 4 * SZ_KV);
  float* eo = (float*)r2;

  u16* ln2o    = (u16*)alloc((size_t)TTOK * HDIM * 2);
  float* ln2f  = (float*)alloc((size_t)TTOK * HDIM * 4);
  int* tidx    = (int*)alloc(TTOK * 2 * 4);
  float* tp    = (float*)alloc(TTOK * 2 * 4);
  int* rowsIdx = (int*)alloc(TTOK * 2 * 4);
  float* wvals = (float*)alloc(TTOK * 2 * 4);
  int* invm    = (int*)alloc(TTOK * 2 * 4);
  int* cnt     = (int*)alloc(8 * 4);
  int* offs    = (int*)alloc(9 * 4);
  int* cur     = (int*)alloc(8 * 4);

  hipMemsetAsync(cnt, 0, 8 * 4, stream);

  // weight prep
  cvt_w3_kernel<<<(QKVO * HDIM / 4 + 255) / 256, 256, 0, stream>>>(wqkv, wqkv3, QKVO * HDIM / 4);
  cvt_w3_kernel<<<(HDIM * HDIM / 4 + 255) / 256, 256, 0, stream>>>(wproj, wproj3, HDIM * HDIM / 4);
  dim3 tb(32, 8);
  transpose_cvt_kernel<<<dim3(FDIM / 32, HDIM / 32, NEXP), tb, 0, stream>>>(w1, w1t, HDIM, FDIM);
  transpose_cvt_kernel<<<dim3(HDIM / 32, FDIM / 32, NEXP), tb, 0, stream>>>(w2, w2t, FDIM, HDIM);

  // LN1 -> 3-wide split
  ln_kernel<<<TTOK, 256, 0, stream>>>(hs, ln1w, ln1b, ln1_3, nullptr, nullptr);

  // QKV gemm (K=3072) with fused split-scatter epilogue
  gemm_bt<0><<<dim3(QKVO / 128, TTOK / 128), 256, 0, stream>>>(
      ln1_3, wqkv3, QKVO, K3, TTOK, nullptr, nullptr,
      Qbh, Qbl, Kbh, Kbl, Vbh, Vbl, nullptr, nullptr, nullptr);

  attn_kernel<<<dim3(BATCH * NHEADS, SLEN / 64), 256, 0, stream>>>(
      Qbh, Qbl, Kbh, Kbl, Vbh, Vbl, attn3);

  // proj gemm (K=3072) + residual
  gemm_bt<1><<<dim3(HDIM / 128, TTOK / 128), 256, 0, stream>>>(
      attn3, wproj3, HDIM, K3, TTOK, hs, out,
      nullptr, nullptr, nullptr, nullptr, nullptr, nullptr, nullptr, nullptr, nullptr);

  // LN2 -> bf16 (for MoE) + fp32 (for router)
  ln_kernel<<<TTOK, 256, 0, stream>>>(out, ln2w, ln2b, nullptr, ln2o, ln2f);

  router_kernel<<<TTOK, 256, 0, stream>>>(ln2f, wrout, tidx, tp, cnt);
  offsets_kernel<<<1, 64, 0, stream>>>(cnt, offs, cur);
  assign_kernel<<<TTOK / 256, 256, 0, stream>>>(tidx, tp, offs, cur, rowsIdx, wvals, invm);

  gemm_bt<2><<<dim3(FDIM / 128, TTOK / 128, NEXP), 256, 0, stream>>>(
      ln2o, w1t, FDIM, HDIM, 0, nullptr, nullptr,
      hmid, nullptr, nullptr, nullptr, nullptr, nullptr, offs, rowsIdx, nullptr);

  gemm_bt<3><<<dim3(HDIM / 128, TTOK / 128, NEXP), 256, 0, stream>>>(
      hmid, w2t, HDIM, FDIM, 0, nullptr, eo,
      nullptr, nullptr, nullptr, nullptr, nullptr, nullptr, offs, nullptr, wvals);

  combine_kernel<<<TTOK, 256, 0, stream>>>(out, eo, invm);
}

// Round 4
// 484.516 us; speedup vs baseline: 1.4263x; 1.2375x over previous
//
#include <hip/hip_runtime.h>
#include <stdint.h>

typedef unsigned short u16;
typedef float f32x4 __attribute__((ext_vector_type(4)));
typedef __bf16 bf16x8 __attribute__((ext_vector_type(8)));
typedef u16 u16x8 __attribute__((ext_vector_type(8)));

#define NHEADS 16
#define NKV 4
#define HD 64
#define HDIM 1024
#define FDIM 2048
#define SLEN 1024
#define BATCH 4
#define TTOK 4096
#define NEXP 8
#define QKVO 1536
#define K3 3072
#define NREP 32

__device__ __forceinline__ u16 f2bf(float f) {
  union { float f; uint32_t u; } c; c.f = f;
  uint32_t u = c.u;
  return (u16)((u + 0x7FFFu + ((u >> 16) & 1u)) >> 16);
}
__device__ __forceinline__ float bf2f(u16 h) {
  union { uint32_t u; float f; } c; c.u = ((uint32_t)h) << 16; return c.f;
}
__device__ __forceinline__ void split2(float v, u16& h, u16& l) {
  h = f2bf(v);
  l = f2bf(v - bf2f(h));
}

__device__ __forceinline__ f32x4 mfma16(bf16x8 a, bf16x8 b, f32x4 c) {
  return __builtin_amdgcn_mfma_f32_16x16x32_bf16(a, b, c, 0, 0, 0);
}

__device__ __forceinline__ bf16x8 lds_frag(const u16* base) {
  u16x8 v = *(const u16x8*)base;
  return __builtin_bit_cast(bf16x8, v);
}

__device__ __forceinline__ void gload_lds16(const void* g, void* l) {
  __builtin_amdgcn_global_load_lds((const __attribute__((address_space(1))) void*)g,
                                   (__attribute__((address_space(3))) void*)l, 16, 0, 0);
}

// ---- fp32 weight [R][1024] -> 3-wide split bf16 [R][3072] = [hi|hi|lo] ----
__global__ __launch_bounds__(256)
void cvt_w3_kernel(const float* __restrict__ in, u16* __restrict__ out, int n4) {
  int i = blockIdx.x * blockDim.x + threadIdx.x;
  if (i >= n4) return;
  float4 v = ((const float4*)in)[i];
  int row = i >> 8;        // 256 float4 per 1024-wide row
  int c = (i & 255) * 4;
  ushort4 h, l;
  split2(v.x, h.x, l.x); split2(v.y, h.y, l.y);
  split2(v.z, h.z, l.z); split2(v.w, h.w, l.w);
  u16* orow = out + (size_t)row * K3 + c;
  *(ushort4*)(orow) = h;
  *(ushort4*)(orow + 1024) = h;
  *(ushort4*)(orow + 2048) = l;
}

// ---- tiled transpose + convert: in [R][C] f32 -> out [C][R] bf16, z = expert ----
__global__ __launch_bounds__(256)
void transpose_cvt_kernel(const float* __restrict__ in, u16* __restrict__ out, int R, int C) {
  __shared__ float tile[32][33];
  size_t eoff = (size_t)blockIdx.z * (size_t)R * (size_t)C;
  in += eoff; out += eoff;
  int c0 = blockIdx.x * 32, r0 = blockIdx.y * 32;
  int tx = threadIdx.x, ty = threadIdx.y;
#pragma unroll
  for (int i = 0; i < 4; i++)
    tile[ty + i * 8][tx] = in[(size_t)(r0 + ty + i * 8) * C + c0 + tx];
  __syncthreads();
#pragma unroll
  for (int i = 0; i < 4; i++)
    out[(size_t)(c0 + ty + i * 8) * R + r0 + tx] = f2bf(tile[tx][ty + i * 8]);
}

// ---- LayerNorm: o3 (3-wide [hi|lo|hi]) OR (obf single + of32) ----
__global__ __launch_bounds__(256)
void ln_kernel(const float* __restrict__ x, const float* __restrict__ w,
               const float* __restrict__ bias, u16* __restrict__ o3,
               u16* __restrict__ obf, float* __restrict__ of32) {
  int t = blockIdx.x, tid = threadIdx.x;
  int wid = tid >> 6, lane = tid & 63;
  float4 v = ((const float4*)(x + (size_t)t * HDIM))[tid];
  float s = v.x + v.y + v.z + v.w;
  float q = v.x * v.x + v.y * v.y + v.z * v.z + v.w * v.w;
#pragma unroll
  for (int mm = 32; mm >= 1; mm >>= 1) {
    s += __shfl_xor(s, mm);
    q += __shfl_xor(q, mm);
  }
  __shared__ float ss[4], qq[4];
  if (lane == 0) { ss[wid] = s; qq[wid] = q; }
  __syncthreads();
  s = ss[0] + ss[1] + ss[2] + ss[3];
  q = qq[0] + qq[1] + qq[2] + qq[3];
  float mu = s * (1.0f / HDIM);
  float var = q * (1.0f / HDIM) - mu * mu;
  float inv = rsqrtf(var + 1e-5f);
  float4 wv = ((const float4*)w)[tid];
  float4 bv = ((const float4*)bias)[tid];
  float y0 = (v.x - mu) * inv * wv.x + bv.x;
  float y1 = (v.y - mu) * inv * wv.y + bv.y;
  float y2 = (v.z - mu) * inv * wv.z + bv.z;
  float y3 = (v.w - mu) * inv * wv.w + bv.w;
  ushort4 h, l;
  split2(y0, h.x, l.x); split2(y1, h.y, l.y);
  split2(y2, h.z, l.z); split2(y3, h.w, l.w);
  if (o3) {
    u16* orow = o3 + (size_t)t * K3 + tid * 4;
    *(ushort4*)(orow) = h;
    *(ushort4*)(orow + 1024) = l;
    *(ushort4*)(orow + 2048) = h;
  }
  if (obf) ((ushort4*)(obf + (size_t)t * HDIM))[tid] = h;
  if (of32) {
    float4 yo; yo.x = y0; yo.y = y1; yo.z = y2; yo.w = y3;
    ((float4*)(of32 + (size_t)t * HDIM))[tid] = yo;
  }
}

// ---- GEMM C[M,N] = A[M,K] * B[N,K]^T, bf16, dbuf, gload_lds ----
// MODE 0: QKV (K=3072 interleaved-split) -> split2 scatter to Q/K/V hi+lo
// MODE 1: proj (K=3072) -> outf = C + resid
// MODE 2: moe w1 (grouped, gathered rows) -> gelu -> o0 bf16
// MODE 3: moe w2 (grouped, contiguous)    -> outf = C * wts
template<int MODE>
__global__ __launch_bounds__(256)
void gemm_bt(const u16* __restrict__ A0, const u16* __restrict__ B0,
             int N, int K, int M,
             const float* __restrict__ resid, float* __restrict__ outf,
             u16* __restrict__ o0, u16* __restrict__ o1, u16* __restrict__ o2,
             u16* __restrict__ o3, u16* __restrict__ o4, u16* __restrict__ o5,
             const int* __restrict__ offs, const int* __restrict__ rowsIdx,
             const float* __restrict__ wts) {
  int tid = threadIdx.x;
  int wid = tid >> 6, lane = tid & 63;
  int l15 = lane & 15, l4 = lane >> 4;
  int bn = blockIdx.x, bm = blockIdx.y, e = blockIdx.z;

  int Me = M, rowBase = 0;
  const u16* A = A0;
  const u16* B = B0;
  if constexpr (MODE == 2 || MODE == 3) {
    int oa = offs[e], ob = offs[e + 1];
    Me = ob - oa; rowBase = oa;
    B = B0 + (size_t)e * (size_t)N * (size_t)K;
    if constexpr (MODE == 3) A = A0 + (size_t)oa * (size_t)K;
  }
  if (bm * 128 >= Me) return;

  __shared__ u16 lsA[2][128 * 64];
  __shared__ u16 lsB[2][128 * 64];

  int slot = tid & 7;
  const u16* aPtr[4];
  const u16* bPtr[4];
#pragma unroll
  for (int i = 0; i < 4; i++) {
    int r = i * 32 + (tid >> 3);
    int sl = slot ^ (r & 7);
    int rg = bm * 128 + r;
    if constexpr (MODE == 2) {
      int rc = rg < Me ? rg : (Me - 1);
      rg = rowsIdx[rowBase + rc];
    } else if constexpr (MODE == 3) {
      rg = rg < Me ? rg : (Me - 1);
    }
    aPtr[i] = A + (size_t)rg * K + sl * 8;
    int ng = bn * 128 + r;
    bPtr[i] = B + (size_t)ng * K + sl * 8;
  }

  int wm = (wid >> 1) * 64, wn = (wid & 1) * 64;
  f32x4 zero4 = {0.f, 0.f, 0.f, 0.f};
  f32x4 acc[4][4];
#pragma unroll
  for (int mi = 0; mi < 4; mi++)
#pragma unroll
    for (int ni = 0; ni < 4; ni++) acc[mi][ni] = zero4;

  int aoff[4][2], boff[4][2];
#pragma unroll
  for (int mi = 0; mi < 4; mi++) {
    int row = wm + mi * 16 + l15;
#pragma unroll
    for (int kk = 0; kk < 2; kk++) {
      int cs = kk * 4 + l4;
      aoff[mi][kk] = row * 64 + ((cs ^ (row & 7)) << 3);
    }
  }
#pragma unroll
  for (int ni = 0; ni < 4; ni++) {
    int row = wn + ni * 16 + l15;
#pragma unroll
    for (int kk = 0; kk < 2; kk++) {
      int cs = kk * 4 + l4;
      boff[ni][kk] = row * 64 + ((cs ^ (row & 7)) << 3);
    }
  }

  int nk = K >> 6;
#pragma unroll
  for (int i = 0; i < 4; i++) {
    gload_lds16(aPtr[i], &lsA[0][(i * 256 + wid * 64) * 8]);
    gload_lds16(bPtr[i], &lsB[0][(i * 256 + wid * 64) * 8]);
  }
  __syncthreads();

  int buf = 0;
  for (int kt = 0; kt < nk; ++kt) {
    if (kt + 1 < nk) {
      int k0 = (kt + 1) << 6;
#pragma unroll
      for (int i = 0; i < 4; i++) {
        gload_lds16(aPtr[i] + k0, &lsA[buf ^ 1][(i * 256 + wid * 64) * 8]);
        gload_lds16(bPtr[i] + k0, &lsB[buf ^ 1][(i * 256 + wid * 64) * 8]);
      }
    }
#pragma unroll
    for (int kk = 0; kk < 2; kk++) {
      bf16x8 af[4], bfr[4];
#pragma unroll
      for (int mi = 0; mi < 4; mi++) af[mi] = lds_frag(&lsA[buf][aoff[mi][kk]]);
#pragma unroll
      for (int ni = 0; ni < 4; ni++) bfr[ni] = lds_frag(&lsB[buf][boff[ni][kk]]);
#pragma unroll
      for (int mi = 0; mi < 4; mi++)
#pragma unroll
        for (int ni = 0; ni < 4; ni++)
          acc[mi][ni] = mfma16(af[mi], bfr[ni], acc[mi][ni]);
    }
    __syncthreads();
    buf ^= 1;
  }

#pragma unroll
  for (int mi = 0; mi < 4; mi++) {
#pragma unroll
    for (int r = 0; r < 4; r++) {
      int m = bm * 128 + wm + mi * 16 + l4 * 4 + r;
      if (m >= Me) continue;
#pragma unroll
      for (int ni = 0; ni < 4; ni++) {
        int n = bn * 128 + wn + ni * 16 + l15;
        float v = acc[mi][ni][r];
        if constexpr (MODE == 0) {
          u16 hh, ll; split2(v, hh, ll);
          int sq = m >> 2, bb = m & 3;
          int d = n & 63;
          if (n < 1024) {
            int hd = n >> 6;
            size_t o = ((size_t)(bb * NHEADS + hd) * SLEN + sq) * HD + d;
            o0[o] = hh; o1[o] = ll;
          } else if (n < 1280) {
            int hd = (n - 1024) >> 6;
            size_t o = ((size_t)(bb * NKV + hd) * SLEN + sq) * HD + d;
            o2[o] = hh; o3[o] = ll;
          } else {
            int hd = (n - 1280) >> 6;
            size_t o = ((size_t)(bb * NKV + hd) * SLEN + sq) * HD + d;
            o4[o] = hh; o5[o] = ll;
          }
        } else if constexpr (MODE == 1) {
          size_t idx = (size_t)m * HDIM + n;
          outf[idx] = v + resid[idx];
        } else if constexpr (MODE == 2) {
          float g = 0.5f * v * (1.0f + tanhf(0.7978845608f * (v + 0.044715f * v * v * v)));
          o0[(size_t)(rowBase + m) * FDIM + n] = f2bf(g);
        } else {
          outf[(size_t)(rowBase + m) * HDIM + n] = v * wts[rowBase + m];
        }
      }
    }
  }
}

// ---- flash attention, causal, GQA, split precision, dbuf-K, prefetch-V ----
__global__ __launch_bounds__(256)
void attn_kernel(const u16* __restrict__ Qh_, const u16* __restrict__ Ql_,
                 const u16* __restrict__ Kh_, const u16* __restrict__ Kl_,
                 const u16* __restrict__ Vh_, const u16* __restrict__ Vl_,
                 u16* __restrict__ A3) {
  int bh = blockIdx.x;   // fast dim = bh for CU load balance across qt
  int qt = blockIdx.y;
  int b = bh >> 4, h = bh & 15, kh = h >> 2;
  int tid = threadIdx.x, wid = tid >> 6, lane = tid & 63;
  int l15 = lane & 15, l4 = lane >> 4;
  int slot = tid & 7;

  size_t qoff = ((size_t)(b * NHEADS + h) * SLEN) * HD;
  size_t koff = ((size_t)(b * NKV + kh) * SLEN) * HD;
  const u16* Qh = Qh_ + qoff;
  const u16* Ql = Ql_ + qoff;
  const u16* Kh = Kh_ + koff;
  const u16* Kl = Kl_ + koff;
  const u16* Vh = Vh_ + koff;
  const u16* Vl = Vl_ + koff;

  __shared__ u16 KtH[2][4096], KtL[2][4096];
  __shared__ u16 VtH[4096], VtL[4096];
  __shared__ u16 PtH[4][1024], PtL[4][1024];

  int qrow = qt * 64 + wid * 16 + l15;
  bf16x8 qfh[2], qfl[2];
#pragma unroll
  for (int kk = 0; kk < 2; kk++) {
    u16x8 vh = *(const u16x8*)(Qh + (size_t)qrow * HD + kk * 32 + l4 * 8);
    u16x8 vl = *(const u16x8*)(Ql + (size_t)qrow * HD + kk * 32 + l4 * 8);
    qfh[kk] = __builtin_bit_cast(bf16x8, vh);
    qfl[kk] = __builtin_bit_cast(bf16x8, vl);
  }

  int kr0 = tid >> 3;
  int kr1 = 32 + (tid >> 3);
  int sl0 = slot ^ (kr0 & 7);
  int sl1 = slot ^ (kr1 & 7);
  int kdst0 = (0 * 256 + wid * 64) * 8;
  int kdst1 = (1 * 256 + wid * 64) * 8;

#define STAGE_K(kt_, bf_)                                                     \
  {                                                                           \
    size_t s0 = (size_t)((kt_)*64 + kr0) * HD + sl0 * 8;                      \
    size_t s1 = (size_t)((kt_)*64 + kr1) * HD + sl1 * 8;                      \
    gload_lds16(Kh + s0, &KtH[bf_][kdst0]);                                   \
    gload_lds16(Kl + s0, &KtL[bf_][kdst0]);                                   \
    gload_lds16(Kh + s1, &KtH[bf_][kdst1]);                                   \
    gload_lds16(Kl + s1, &KtL[bf_][kdst1]);                                   \
  }

#define LOAD_V(kt_, vh_, vl_)                                                 \
  {                                                                           \
    _Pragma("unroll") for (int i = 0; i < 2; i++) {                           \
      int kv = i * 32 + (tid >> 3);                                           \
      (vh_)[i] = *(const uint4*)(Vh + (size_t)((kt_)*64 + kv) * HD + slot * 8);\
      (vl_)[i] = *(const uint4*)(Vl + (size_t)((kt_)*64 + kv) * HD + slot * 8);\
    }                                                                         \
  }

#define SCATTER_V(vh_, vl_)                                                   \
  {                                                                           \
    _Pragma("unroll") for (int i = 0; i < 2; i++) {                           \
      int kv = i * 32 + (tid >> 3);                                           \
      const u16* ph = (const u16*)&(vh_)[i];                                  \
      const u16* pl = (const u16*)&(vl_)[i];                                  \
      _Pragma("unroll") for (int j = 0; j < 8; j++) {                         \
        int d = slot * 8 + j;                                                 \
        int g = ((kv >> 3) ^ (d & 7) ^ (d >> 3)) & 7;                         \
        int addr = d * 64 + (g << 3) + (kv & 7);                              \
        VtH[addr] = ph[j];                                                    \
        VtL[addr] = pl[j];                                                    \
      }                                                                       \
    }                                                                         \
  }

  uint4 vH[2], vL[2];
  STAGE_K(0, 0);
  LOAD_V(0, vH, vL);
  SCATTER_V(vH, vL);
  __syncthreads();

  f32x4 zero4 = {0.f, 0.f, 0.f, 0.f};
  f32x4 oacc[4];
#pragma unroll
  for (int nf = 0; nf < 4; nf++) oacc[nf] = zero4;
  float mrun[4], lrun[4];
#pragma unroll
  for (int r = 0; r < 4; r++) { mrun[r] = -1e30f; lrun[r] = 0.f; }

  int buf = 0;
  for (int kt = 0; kt <= qt; ++kt) {
    int kv0 = kt * 64;
    if (kt < qt) {
      STAGE_K(kt + 1, buf ^ 1);
      LOAD_V(kt + 1, vH, vL);
    }

    f32x4 sacc[4];
#pragma unroll
    for (int nf = 0; nf < 4; nf++) sacc[nf] = zero4;
#pragma unroll
    for (int kk = 0; kk < 2; kk++) {
#pragma unroll
      for (int nf = 0; nf < 4; nf++) {
        int krow = nf * 16 + l15;
        int ka = krow * 64 + (((kk * 4 + l4) ^ (krow & 7)) << 3);
        bf16x8 kfh = lds_frag(&KtH[buf][ka]);
        bf16x8 kfl = lds_frag(&KtL[buf][ka]);
        sacc[nf] = mfma16(qfh[kk], kfh, sacc[nf]);
        sacc[nf] = mfma16(qfh[kk], kfl, sacc[nf]);
        sacc[nf] = mfma16(qfl[kk], kfh, sacc[nf]);
      }
    }

    bool diag = (kt == qt);
    float tm[4];
#pragma unroll
    for (int r = 0; r < 4; r++) tm[r] = -1e30f;
#pragma unroll
    for (int nf = 0; nf < 4; nf++) {
#pragma unroll
      for (int r = 0; r < 4; r++) {
        float s = sacc[nf][r] * 0.125f;
        if (diag) {
          int qg = qt * 64 + wid * 16 + l4 * 4 + r;
          int kg = kv0 + nf * 16 + l15;
          if (kg > qg) s = -1e30f;
        }
        sacc[nf][r] = s;
        tm[r] = fmaxf(tm[r], s);
      }
    }
#pragma unroll
    for (int mm = 1; mm < 16; mm <<= 1) {
#pragma unroll
      for (int r = 0; r < 4; r++) tm[r] = fmaxf(tm[r], __shfl_xor(tm[r], mm));
    }
    float ts[4];
#pragma unroll
    for (int r = 0; r < 4; r++) {
      float mn = fmaxf(mrun[r], tm[r]);
      float al = __expf(mrun[r] - mn);
      mrun[r] = mn;
      lrun[r] *= al;
#pragma unroll
      for (int nf = 0; nf < 4; nf++) oacc[nf][r] *= al;
      ts[r] = 0.f;
    }
#pragma unroll
    for (int nf = 0; nf < 4; nf++) {
#pragma unroll
      for (int r = 0; r < 4; r++) {
        float p = __expf(sacc[nf][r] - mrun[r]);
        sacc[nf][r] = p;
        ts[r] += p;
      }
    }
#pragma unroll
    for (int mm = 1; mm < 16; mm <<= 1) {
#pragma unroll
      for (int r = 0; r < 4; r++) ts[r] += __shfl_xor(ts[r], mm);
    }
#pragma unroll
    for (int r = 0; r < 4; r++) lrun[r] += ts[r];

#pragma unroll
    for (int nf = 0; nf < 4; nf++) {
#pragma unroll
      for (int r = 0; r < 4; r++) {
        int qrl = l4 * 4 + r;
        int kv = nf * 16 + l15;
        int g = ((kv >> 3) ^ (qrl & 7) ^ (qrl >> 3)) & 7;
        int addr = qrl * 64 + (g << 3) + (kv & 7);
        u16 hh, ll;
        split2(sacc[nf][r], hh, ll);
        PtH[wid][addr] = hh;
        PtL[wid][addr] = ll;
      }
    }
#pragma unroll
    for (int s2 = 0; s2 < 2; s2++) {
      int cs = s2 * 4 + l4;
      int pa = l15 * 64 + ((((cs ^ (l15 & 7) ^ (l15 >> 3))) & 7) << 3);
      bf16x8 pfh = lds_frag(&PtH[wid][pa]);
      bf16x8 pfl = lds_frag(&PtL[wid][pa]);
#pragma unroll
      for (int nf = 0; nf < 4; nf++) {
        int d = nf * 16 + l15;
        int va = d * 64 + ((((cs ^ (d & 7) ^ (d >> 3))) & 7) << 3);
        bf16x8 vfh = lds_frag(&VtH[va]);
        bf16x8 vfl = lds_frag(&VtL[va]);
        oacc[nf] = mfma16(pfh, vfh, oacc[nf]);
        oacc[nf] = mfma16(pfh, vfl, oacc[nf]);
        oacc[nf] = mfma16(pfl, vfh, oacc[nf]);
      }
    }

    __syncthreads();
    if (kt < qt) {
      SCATTER_V(vH, vL);
    }
    __syncthreads();
    buf ^= 1;
  }

#pragma unroll
  for (int r = 0; r < 4; r++) {
    float invl = 1.0f / lrun[r];
    int qg = qt * 64 + wid * 16 + l4 * 4 + r;
    size_t tb = ((size_t)qg * BATCH + b) * K3 + h * HD;
#pragma unroll
    for (int nf = 0; nf < 4; nf++) {
      u16 hh, ll;
      split2(oacc[nf][r] * invl, hh, ll);
      size_t o = tb + nf * 16 + l15;
      A3[o] = hh;
      A3[o + 1024] = ll;
      A3[o + 2048] = hh;
    }
  }
#undef STAGE_K
#undef LOAD_V
#undef SCATTER_V
}

// ---- router: logits, softmax, top-2 (NO global atomics) ----
__global__ __launch_bounds__(256)
void router_kernel(const float* __restrict__ x, const float* __restrict__ rw,
                   int* __restrict__ tidx, float* __restrict__ tp) {
  int t = blockIdx.x, tid = threadIdx.x;
  int wid = tid >> 6, lane = tid & 63;
  float4 xv = ((const float4*)(x + (size_t)t * HDIM))[tid];
  __shared__ float part[8][4];
  __shared__ float lg[8];
#pragma unroll
  for (int e = 0; e < 8; e++) {
    float4 wv = ((const float4*)(rw + (size_t)e * HDIM))[tid];
    float d = xv.x * wv.x + xv.y * wv.y + xv.z * wv.z + xv.w * wv.w;
#pragma unroll
    for (int mm = 32; mm >= 1; mm >>= 1) d += __shfl_xor(d, mm);
    if (lane == 0) part[e][wid] = d;
  }
  __syncthreads();
  if (tid < 8) lg[tid] = part[tid][0] + part[tid][1] + part[tid][2] + part[tid][3];
  __syncthreads();
  if (tid == 0) {
    float mx = lg[0];
#pragma unroll
    for (int e = 1; e < 8; e++) mx = fmaxf(mx, lg[e]);
    float g[8]; float se = 0.f;
#pragma unroll
    for (int e = 0; e < 8; e++) { g[e] = __expf(lg[e] - mx); se += g[e]; }
    float inv = 1.0f / se;
#pragma unroll
    for (int e = 0; e < 8; e++) g[e] *= inv;
    int i0 = 0; float v0 = g[0];
#pragma unroll
    for (int e = 1; e < 8; e++) if (g[e] > v0) { v0 = g[e]; i0 = e; }
    int i1 = -1; float v1 = -1.f;
#pragma unroll
    for (int e = 0; e < 8; e++) if (e != i0 && g[e] > v1) { v1 = g[e]; i1 = e; }
    tidx[t * 2] = i0; tidx[t * 2 + 1] = i1;
    tp[t * 2] = v0; tp[t * 2 + 1] = v1;
  }
}

// ---- histogram (expert x rep) + offsets + repBase; zero curRep. One block. ----
__global__ __launch_bounds__(256)
void hist_offsets_kernel(const int* __restrict__ tidx, int* __restrict__ offs,
                         int* __restrict__ repBase, int* __restrict__ curRep) {
  __shared__ int hist[NEXP * NREP];
  __shared__ int eoffs[NEXP + 1];
  int tid = threadIdx.x;
  hist[tid] = 0;
  __syncthreads();
  for (int i = tid; i < TTOK; i += 256) {
    int rep = i & (NREP - 1);
    atomicAdd(&hist[tidx[2 * i] * NREP + rep], 1);
    atomicAdd(&hist[tidx[2 * i + 1] * NREP + rep], 1);
  }
  __syncthreads();
  if (tid == 0) {
    int a = 0;
    for (int e = 0; e < NEXP; e++) {
      eoffs[e] = a;
      for (int r = 0; r < NREP; r++) a += hist[e * NREP + r];
    }
    eoffs[NEXP] = a;
  }
  __syncthreads();
  if (tid < NEXP) {
    int a = eoffs[tid];
    for (int r = 0; r < NREP; r++) {
      repBase[tid * NREP + r] = a;
      a += hist[tid * NREP + r];
    }
  }
  if (tid < NEXP + 1) offs[tid] = eoffs[tid];
  curRep[tid] = 0;
}

// ---- assign: spread atomics over NEXP*NREP counters ----
__global__ __launch_bounds__(256)
void assign_kernel(const int* __restrict__ tidx, const float* __restrict__ tp,
                   const int* __restrict__ repBase, int* __restrict__ curRep,
                   int* __restrict__ rowsIdx, float* __restrict__ wvals,
                   int* __restrict__ inv) {
  int t = blockIdx.x * blockDim.x + threadIdx.x;
  if (t >= TTOK) return;
  int rep = t & (NREP - 1);
#pragma unroll
  for (int k = 0; k < 2; k++) {
    int e = tidx[t * 2 + k];
    int s = atomicAdd(&curRep[e * NREP + rep], 1);
    int pos = repBase[e * NREP + rep] + s;
    rowsIdx[pos] = t;
    wvals[pos] = tp[t * 2 + k];
    inv[t * 2 + k] = pos;
  }
}

__global__ __launch_bounds__(256)
void combine_kernel(float* __restrict__ out, const float* __restrict__ eo,
                    const int* __restrict__ inv) {
  int t = blockIdx.x, c = threadIdx.x;
  int r0 = inv[t * 2], r1 = inv[t * 2 + 1];
  float4* o = (float4*)(out + (size_t)t * HDIM);
  const float4* e0 = (const float4*)(eo + (size_t)r0 * HDIM);
  const float4* e1 = (const float4*)(eo + (size_t)r1 * HDIM);
  float4 v = o[c];
  float4 a = e0[c];
  float4 bb = e1[c];
  v.x += a.x + bb.x; v.y += a.y + bb.y; v.z += a.z + bb.z; v.w += a.w + bb.w;
  o[c] = v;
}

extern "C" void kernel_launch(void* const* d_in, const int* in_sizes, int n_in,
                              void* d_out, int out_size, void* d_ws, size_t ws_size,
                              hipStream_t stream) {
  (void)in_sizes; (void)n_in; (void)out_size; (void)ws_size;
  const float* hs    = (const float*)d_in[0];
  const float* ln1w  = (const float*)d_in[1];
  const float* ln1b  = (const float*)d_in[2];
  const float* ln2w  = (const float*)d_in[3];
  const float* ln2b  = (const float*)d_in[4];
  const float* wqkv  = (const float*)d_in[5];
  const float* wproj = (const float*)d_in[6];
  const float* wrout = (const float*)d_in[7];
  const float* w1    = (const float*)d_in[8];
  const float* w2    = (const float*)d_in[9];
  float* out = (float*)d_out;

  char* base = (char*)d_ws;
  size_t off = 0;
  auto alloc = [&](size_t n) { void* r = base + off; off += (n + 255) & ~(size_t)255; return r; };

  const size_t SZ_W1T   = (size_t)NEXP * FDIM * HDIM * 2;
  const size_t SZ_W2T   = (size_t)NEXP * HDIM * FDIM * 2;
  const size_t SZ_WP3   = (size_t)HDIM * K3 * 2;
  const size_t SZ_LN13  = (size_t)TTOK * K3 * 2;
  const size_t SZ_WQ3   = (size_t)QKVO * K3 * 2;
  const size_t SZ_HMID  = (size_t)TTOK * 2 * FDIM * 2;
  const size_t SZ_Q     = (size_t)BATCH * NHEADS * SLEN * HD * 2;
  const size_t SZ_KV    = (size_t)BATCH * NKV * SLEN * HD * 2;
  const size_t SZ_A3    = (size_t)TTOK * K3 * 2;
  const size_t SZ_EO    = (size_t)TTOK * 2 * HDIM * 4;

  u16* w1t     = (u16*)alloc(SZ_W1T);
  u16* w2t     = (u16*)alloc(SZ_W2T);
  u16* wproj3  = (u16*)alloc(SZ_WP3);

  size_t r1sz = SZ_LN13 + SZ_WQ3;
  if (SZ_HMID > r1sz) r1sz = SZ_HMID;
  char* r1 = (char*)alloc(r1sz);
  u16* ln1_3 = (u16*)r1;
  u16* wqkv3 = (u16*)(r1 + SZ_LN13);
  u16* hmid  = (u16*)r1;

  size_t r2sz = 2 * SZ_Q + 4 * SZ_KV + SZ_A3;
  if (SZ_EO > r2sz) r2sz = SZ_EO;
  char* r2 = (char*)alloc(r2sz);
  u16* Qbh = (u16*)r2;
  u16* Qbl = (u16*)(r2 + SZ_Q);
  u16* Kbh = (u16*)(r2 + 2 * SZ_Q);
  u16* Kbl = (u16*)(r2 + 2 * SZ_Q + SZ_KV);
  u16* Vbh = (u16*)(r2 + 2 * SZ_Q + 2 * SZ_KV);
  u16* Vbl = (u16*)(r2 + 2 * SZ_Q + 3 * SZ_KV);
  u16* attn3 = (u16*)(r2 + 2 * SZ_Q + 4 * SZ_KV);
  float* eo = (float*)r2;

  u16* ln2o    = (u16*)alloc((size_t)TTOK * HDIM * 2);
  float* ln2f  = (float*)alloc((size_t)TTOK * HDIM * 4);
  int* tidx    = (int*)alloc(TTOK * 2 * 4);
  float* tp    = (float*)alloc(TTOK * 2 * 4);
  int* rowsIdx = (int*)alloc(TTOK * 2 * 4);
  float* wvals = (float*)alloc(TTOK * 2 * 4);
  int* invm    = (int*)alloc(TTOK * 2 * 4);
  int* offs    = (int*)alloc((NEXP + 1) * 4);
  int* repBase = (int*)alloc(NEXP * NREP * 4);
  int* curRep  = (int*)alloc(NEXP * NREP * 4);

  // weight prep
  cvt_w3_kernel<<<(QKVO * HDIM / 4 + 255) / 256, 256, 0, stream>>>(wqkv, wqkv3, QKVO * HDIM / 4);
  cvt_w3_kernel<<<(HDIM * HDIM / 4 + 255) / 256, 256, 0, stream>>>(wproj, wproj3, HDIM * HDIM / 4);
  dim3 tb(32, 8);
  transpose_cvt_kernel<<<dim3(FDIM / 32, HDIM / 32, NEXP), tb, 0, stream>>>(w1, w1t, HDIM, FDIM);
  transpose_cvt_kernel<<<dim3(HDIM / 32, FDIM / 32, NEXP), tb, 0, stream>>>(w2, w2t, FDIM, HDIM);

  ln_kernel<<<TTOK, 256, 0, stream>>>(hs, ln1w, ln1b, ln1_3, nullptr, nullptr);

  gemm_bt<0><<<dim3(QKVO / 128, TTOK / 128), 256, 0, stream>>>(
      ln1_3, wqkv3, QKVO, K3, TTOK, nullptr, nullptr,
      Qbh, Qbl, Kbh, Kbl, Vbh, Vbl, nullptr, nullptr, nullptr);

  attn_kernel<<<dim3(BATCH * NHEADS, SLEN / 64), 256, 0, stream>>>(
      Qbh, Qbl, Kbh, Kbl, Vbh, Vbl, attn3);

  gemm_bt<1><<<dim3(HDIM / 128, TTOK / 128), 256, 0, stream>>>(
      attn3, wproj3, HDIM, K3, TTOK, hs, out,
      nullptr, nullptr, nullptr, nullptr, nullptr, nullptr, nullptr, nullptr, nullptr);

  ln_kernel<<<TTOK, 256, 0, stream>>>(out, ln2w, ln2b, nullptr, ln2o, ln2f);

  router_kernel<<<TTOK, 256, 0, stream>>>(ln2f, wrout, tidx, tp);
  hist_offsets_kernel<<<1, 256, 0, stream>>>(tidx, offs, repBase, curRep);
  assign_kernel<<<TTOK / 256, 256, 0, stream>>>(tidx, tp, repBase, curRep, rowsIdx, wvals, invm);

  gemm_bt<2><<<dim3(FDIM / 128, TTOK / 128, NEXP), 256, 0, stream>>>(
      ln2o, w1t, FDIM, HDIM, 0, nullptr, nullptr,
      hmid, nullptr, nullptr, nullptr, nullptr, nullptr, offs, rowsIdx, nullptr);

  gemm_bt<3><<<dim3(HDIM / 128, TTOK / 128, NEXP), 256, 0, stream>>>(
      hmid, w2t, HDIM, FDIM, 0, nullptr, eo,
      nullptr, nullptr, nullptr, nullptr, nullptr, nullptr, offs, nullptr, wvals);

  combine_kernel<<<TTOK, 256, 0, stream>>>(out, eo, invm);
}